// Round 1
// baseline (45368.509 us; speedup 1.0000x reference)
//
#include <hip/hip_runtime.h>
#include <cstdint>
#include <cstddef>

#define HW 512
#define SPATIAL (HW*HW)              // 262144
#define BATCH 16
#define CH 3
#define NPLANE (BATCH*CH)            // 48
#define NELEM ((size_t)NPLANE*SPATIAL) // 12582912
#define K_SELECT 78643
#define NITER 160
#define CAP_TIES 4096
#define NSLOT 64

static const size_t OFF_R    = 0;
static const size_t OFF_PA   = NELEM*4;
static const size_t OFF_PB   = NELEM*8;
static const size_t OFF_RRP  = NELEM*12;                                  // double[(NITER+1)*NSLOT]
static const size_t OFF_PAPP = OFF_RRP + (size_t)(NITER+1)*NSLOT*8;       // double[NITER*NSLOT]
static const size_t OFF_HC   = OFF_PAPP + (size_t)NITER*NSLOT*8;          // int[16][1024]
static const size_t OFF_HF   = OFF_HC + (size_t)BATCH*1024*4;             // int[16][1024]
static const size_t OFF_SEL  = OFF_HF + (size_t)BATCH*1024*4;             // int[16][4]: cb, above, T, need
static const size_t OFF_TC   = OFF_SEL + (size_t)BATCH*4*4;               // int[16]
static const size_t OFF_TL   = OFF_TC + 64;                               // int[16][CAP_TIES]

// ---------------- reductions ----------------
__device__ __forceinline__ double wave_block_reduce256(double v, int tid){
  #pragma unroll
  for (int o=32;o>0;o>>=1) v += __shfl_down(v, o, 64);
  __shared__ double sred[4];
  if ((tid & 63)==0) sred[tid>>6] = v;
  __syncthreads();
  double s = 0.0;
  if (tid==0) s = sred[0]+sred[1]+sred[2]+sred[3];
  return s; // valid only on tid 0
}

// ---------------- mask pipeline ----------------
__global__ __launch_bounds__(256) void k_hist_coarse(const int* __restrict__ smap, int* __restrict__ hist){
  __shared__ int h[1024];
  int tid = threadIdx.x;
  for (int j=tid;j<1024;j+=256) h[j]=0;
  __syncthreads();
  int b = blockIdx.y;
  int base = b*SPATIAL + blockIdx.x*4096;
  #pragma unroll
  for (int e=0;e<16;e++){
    int v = smap[base + e*256 + tid];
    atomicAdd(&h[v>>10], 1);
  }
  __syncthreads();
  for (int j=tid;j<1024;j+=256){ int c=h[j]; if(c) atomicAdd(&hist[b*1024+j], c); }
}

__global__ void k_select_coarse(const int* __restrict__ hist, int* __restrict__ sel){
  int b = blockIdx.x;
  const int* h = hist + b*1024;
  int acc=0;
  for (int bin=1023;bin>=0;bin--){
    int c=h[bin]; acc+=c;
    if (acc>=K_SELECT){ sel[b*4+0]=bin; sel[b*4+1]=acc-c; break; }
  }
}

__global__ __launch_bounds__(256) void k_hist_fine(const int* __restrict__ smap, const int* __restrict__ sel, int* __restrict__ hist){
  __shared__ int h[1024];
  int tid=threadIdx.x;
  for (int j=tid;j<1024;j+=256) h[j]=0;
  __syncthreads();
  int b=blockIdx.y;
  int cb = sel[b*4+0];
  int base = b*SPATIAL + blockIdx.x*4096;
  #pragma unroll
  for (int e=0;e<16;e++){
    int v = smap[base+e*256+tid];
    if ((v>>10)==cb) atomicAdd(&h[v&1023],1);
  }
  __syncthreads();
  for (int j=tid;j<1024;j+=256){ int c=h[j]; if(c) atomicAdd(&hist[b*1024+j],c); }
}

__global__ void k_select_fine(const int* __restrict__ hist, int* __restrict__ sel){
  int b=blockIdx.x;
  const int* h=hist+b*1024;
  int cb=sel[b*4+0];
  int acc=sel[b*4+1];
  for (int j=1023;j>=0;j--){
    int c=h[j]; acc+=c;
    if (acc>=K_SELECT){ sel[b*4+2]=(cb<<10)|j; sel[b*4+3]=K_SELECT-(acc-c); break; }
  }
}

__global__ __launch_bounds__(256) void k_mask_init(const int* __restrict__ smap, const int* __restrict__ sel,
                                                   float* __restrict__ mask, int* __restrict__ tiecnt, int* __restrict__ tielist){
  int idx = blockIdx.x*256+threadIdx.x;  // < 4194304
  int b = idx>>18;
  int v = smap[idx];
  int T = sel[b*4+2];
  float m = (v>T)?0.f:1.f;
  if (v==T){
    int t = atomicAdd(&tiecnt[b],1);
    if (t<CAP_TIES) tielist[b*CAP_TIES+t] = idx & (SPATIAL-1);
  }
  mask[idx]=m;
}

__global__ __launch_bounds__(256) void k_tie_fix(const int* __restrict__ sel, const int* __restrict__ tiecnt,
                                                 const int* __restrict__ tielist, float* __restrict__ mask){
  int b=blockIdx.x;
  int n = tiecnt[b]; if (n>CAP_TIES) n=CAP_TIES;
  int need = sel[b*4+3];
  for (int e=threadIdx.x; e<n; e+=256){
    int me = tielist[b*CAP_TIES+e];
    int rank=0;
    for (int j=0;j<n;j++) rank += (tielist[b*CAP_TIES+j] < me) ? 1:0;
    if (rank<need) mask[b*SPATIAL+me]=0.f;
  }
}

// ---------------- stencil helper ----------------
template<typename F>
__device__ __forceinline__ void stencil_gather(int y,int x,int sp,F val,float& acc,float& sw){
  const float WE=(float)(1.0/6.0), WC=(float)(1.0/12.0);
  acc=0.f; sw=0.f;
  bool ym=y>0, yp=y<HW-1, xm=x>0, xp=x<HW-1;
  if(ym){ sw+=WE; acc+=WE*val(sp-HW);
    if(xm){sw+=WC; acc+=WC*val(sp-HW-1);}
    if(xp){sw+=WC; acc+=WC*val(sp-HW+1);} }
  if(yp){ sw+=WE; acc+=WE*val(sp+HW);
    if(xm){sw+=WC; acc+=WC*val(sp+HW-1);}
    if(xp){sw+=WC; acc+=WC*val(sp+HW+1);} }
  if(xm){ sw+=WE; acc+=WE*val(sp-1); }
  if(xp){ sw+=WE; acc+=WE*val(sp+1); }
}

// ---------------- CG kernels ----------------
__global__ __launch_bounds__(256) void k_rhs(const float* __restrict__ img, const float* __restrict__ mask,
                                             float* __restrict__ r, double* __restrict__ rrp){
  int x = blockIdx.x*64+threadIdx.x;
  int y = blockIdx.y*4+threadIdx.y;
  int bc = blockIdx.z;
  size_t base=(size_t)bc*SPATIAL;
  size_t mb=(size_t)(bc/CH)*SPATIAL;
  int sp=y*HW+x;
  auto val=[&](int j)->float{ return mask[mb+j]*img[base+j]; };
  float acc,sw;
  stencil_gather(y,x,sp,val,acc,sw);
  (void)sw;
  float unk = (mask[mb+sp]==0.f)?1.f:0.f;
  float rv = unk*acc;
  r[base+sp]=rv;
  int tid=threadIdx.y*64+threadIdx.x;
  double s=wave_block_reduce256((double)rv*(double)rv, tid);
  if (tid==0){
    int slot=(blockIdx.x + blockIdx.y*8 + blockIdx.z*1024)&(NSLOT-1);
    atomicAdd(&rrp[slot], s);
  }
}

// p_new = r + beta*p_old ; Ap = unk*(S*p_new - stencil(p_new)) computed on the fly; accumulate p.Ap
__global__ __launch_bounds__(256) void k_pup_apply(const float* __restrict__ r, const float* __restrict__ p_old,
    float* __restrict__ p_new, const float* __restrict__ mask,
    const double* __restrict__ rrp, double* __restrict__ papp, int iter){
  int x=blockIdx.x*64+threadIdx.x, y=blockIdx.y*4+threadIdx.y, bc=blockIdx.z;
  size_t base=(size_t)bc*SPATIAL, mb=(size_t)(bc/CH)*SPATIAL;
  int sp=y*HW+x;
  float bf=0.f;
  if (iter>0){
    double rprev=0.0, rcur=0.0;
    #pragma unroll
    for(int j=0;j<NSLOT;j++){ rprev+=rrp[(size_t)(iter-1)*NSLOT+j]; rcur+=rrp[(size_t)iter*NSLOT+j]; }
    bf = (rprev>0.0)? (float)(rcur/rprev) : 0.f;
  }
  auto val=[&](int j)->float{
    float v=r[base+j];
    if (iter>0) v += bf*p_old[base+j];
    return v;
  };
  float pc=val(sp);
  float acc,sw; stencil_gather(y,x,sp,val,acc,sw);
  float m=mask[mb+sp];
  float Ap=(m==0.f)? (sw*pc-acc) : 0.f;
  p_new[base+sp]=pc;
  int tid=threadIdx.y*64+threadIdx.x;
  double s=wave_block_reduce256((double)pc*(double)Ap,tid);
  if (tid==0){
    int slot=(blockIdx.x+blockIdx.y*8+blockIdx.z*1024)&(NSLOT-1);
    atomicAdd(&papp[(size_t)iter*NSLOT+slot],s);
  }
}

// x += alpha*p ; r -= alpha*Ap (Ap recomputed from p) ; accumulate r.r
__global__ __launch_bounds__(256) void k_update(float* __restrict__ xv, float* __restrict__ r,
    const float* __restrict__ p, const float* __restrict__ mask,
    double* __restrict__ rrp, const double* __restrict__ papp, int iter){
  double rcur=0.0, pap=0.0;
  #pragma unroll
  for(int j=0;j<NSLOT;j++){ rcur+=rrp[(size_t)iter*NSLOT+j]; pap+=papp[(size_t)iter*NSLOT+j]; }
  float af = (pap!=0.0)? (float)(rcur/pap) : 0.f;
  double part=0.0;
  for (size_t i=(size_t)blockIdx.x*256+threadIdx.x; i<NELEM; i+=(size_t)gridDim.x*256){
    int bc=(int)(i>>18);
    int sp=(int)(i&(SPATIAL-1));
    int y=sp>>9, xx=sp&(HW-1);
    size_t base=(size_t)bc<<18, mb=(size_t)(bc/CH)<<18;
    float pcv=p[i];
    float m=mask[mb+sp];
    float Ap=0.f;
    if (m==0.f){
      auto val=[&](int j)->float{ return p[base+j]; };
      float acc,sw; stencil_gather(y,xx,sp,val,acc,sw);
      Ap=sw*pcv-acc;
    }
    xv[i]+=af*pcv;
    float rn=r[i]-af*Ap;
    r[i]=rn;
    part+=(double)rn*(double)rn;
  }
  double s=wave_block_reduce256(part,(int)threadIdx.x);
  if (threadIdx.x==0){
    int slot=(int)(blockIdx.x&(NSLOT-1));
    atomicAdd(&rrp[(size_t)(iter+1)*NSLOT+slot],s);
  }
}

__global__ __launch_bounds__(256) void k_final(const float* __restrict__ img, const float* __restrict__ noise,
    const float* __restrict__ mask, float* __restrict__ out){
  size_t i=(size_t)blockIdx.x*256+threadIdx.x;
  if (i>=NELEM) return;
  int bc=(int)(i>>18); int sp=(int)(i&(SPATIAL-1));
  size_t mb=(size_t)(bc/CH)<<18;
  float m=mask[mb+sp];
  out[i] = (m!=0.f)? img[i] : out[i] + 0.01f*noise[i];
}

extern "C" void kernel_launch(void* const* d_in, const int* in_sizes, int n_in,
                              void* d_out, int out_size, void* d_ws, size_t ws_size,
                              hipStream_t stream) {
  const float* img  =(const float*)d_in[0];
  const int*   smap =(const int*)d_in[1];
  const float* noise=(const float*)d_in[2];
  float* out=(float*)d_out;
  float* maskout = out + NELEM;          // mask output region (B,H,W)
  char* ws=(char*)d_ws;
  float* r  =(float*)(ws+OFF_R);
  float* pA =(float*)(ws+OFF_PA);
  float* pB =(float*)(ws+OFF_PB);
  double* rrp =(double*)(ws+OFF_RRP);
  double* papp=(double*)(ws+OFF_PAPP);
  int* hc=(int*)(ws+OFF_HC);
  int* hf=(int*)(ws+OFF_HF);
  int* sel=(int*)(ws+OFF_SEL);
  int* tiecnt=(int*)(ws+OFF_TC);
  int* tielist=(int*)(ws+OFF_TL);

  // zero x (lives in d_out imputed region) and scalar/hist region
  hipMemsetAsync(out, 0, NELEM*4, stream);
  hipMemsetAsync(ws+OFF_RRP, 0, OFF_TL-OFF_RRP, stream);

  // mask pipeline
  k_hist_coarse<<<dim3(64,16),256,0,stream>>>(smap,hc);
  k_select_coarse<<<16,1,0,stream>>>(hc,sel);
  k_hist_fine<<<dim3(64,16),256,0,stream>>>(smap,sel,hf);
  k_select_fine<<<16,1,0,stream>>>(hf,sel);
  k_mask_init<<<SPATIAL*BATCH/256,256,0,stream>>>(smap,sel,maskout,tiecnt,tielist);
  k_tie_fix<<<16,256,0,stream>>>(sel,tiecnt,tielist,maskout);

  // rhs -> r ; rr[0]
  dim3 gtile(HW/64, HW/4, NPLANE), btile(64,4);
  k_rhs<<<gtile,btile,0,stream>>>(img,maskout,r,rrp);

  // CG iterations
  for (int i=0;i<NITER;i++){
    float* pin  = (i&1)? pA : pB;
    float* pout = (i&1)? pB : pA;
    k_pup_apply<<<gtile,btile,0,stream>>>(r,pin,pout,maskout,rrp,papp,i);
    k_update<<<2048,256,0,stream>>>(out,r,pout,maskout,rrp,papp,i);
  }

  k_final<<<NELEM/256,256,0,stream>>>(img,noise,maskout,out);
}

// Round 2
// 39814.282 us; speedup vs baseline: 1.1395x; 1.1395x over previous
//
#include <hip/hip_runtime.h>
#include <cstdint>
#include <cstddef>

#define HW 512
#define SPATIAL (HW*HW)              // 262144
#define BATCH 16
#define CH 3
#define NPLANE (BATCH*CH)            // 48
#define NELEM ((size_t)NPLANE*SPATIAL) // 12582912
#define K_SELECT 78643
#define NITER 120
#define CAP_TIES 4096
#define NSLOT 64

typedef _Float16 h16;

// workspace layout (fp16 vectors)
static const size_t OFF_R    = 0;                      // h16[NELEM]
static const size_t OFF_PA   = NELEM*2;                // h16[NELEM]
static const size_t OFF_PB   = NELEM*4;                // h16[NELEM]
static const size_t OFF_BITS = NELEM*6;                // uint32[BATCH*8192] = 512KB
static const size_t OFF_RRP  = OFF_BITS + (size_t)BATCH*8192*4;           // double[(NITER+1)*NSLOT]
static const size_t OFF_PAPP = OFF_RRP + (size_t)(NITER+1)*NSLOT*8;       // double[NITER*NSLOT]
static const size_t OFF_HC   = OFF_PAPP + (size_t)NITER*NSLOT*8;          // int[16][1024]
static const size_t OFF_HF   = OFF_HC + (size_t)BATCH*1024*4;             // int[16][1024]
static const size_t OFF_SEL  = OFF_HF + (size_t)BATCH*1024*4;             // int[16][4]
static const size_t OFF_TC   = OFF_SEL + (size_t)BATCH*4*4;               // int[16]
static const size_t OFF_TL   = OFF_TC + 64;                               // int[16][CAP_TIES]

// ---------------- reductions ----------------
__device__ __forceinline__ double wave_block_reduce256(double v, int tid){
  #pragma unroll
  for (int o=32;o>0;o>>=1) v += __shfl_down(v, o, 64);
  __shared__ double sred[4];
  if ((tid & 63)==0) sred[tid>>6] = v;
  __syncthreads();
  double s = 0.0;
  if (tid==0) s = sred[0]+sred[1]+sred[2]+sred[3];
  return s; // valid only on tid 0
}

// ---------------- mask pipeline ----------------
__global__ __launch_bounds__(256) void k_hist_coarse(const int* __restrict__ smap, int* __restrict__ hist){
  __shared__ int h[1024];
  int tid = threadIdx.x;
  for (int j=tid;j<1024;j+=256) h[j]=0;
  __syncthreads();
  int b = blockIdx.y;
  int base = b*SPATIAL + blockIdx.x*4096;
  #pragma unroll
  for (int e=0;e<16;e++){
    int v = smap[base + e*256 + tid];
    atomicAdd(&h[v>>10], 1);
  }
  __syncthreads();
  for (int j=tid;j<1024;j+=256){ int c=h[j]; if(c) atomicAdd(&hist[b*1024+j], c); }
}

__global__ void k_select_coarse(const int* __restrict__ hist, int* __restrict__ sel){
  int b = blockIdx.x;
  const int* h = hist + b*1024;
  int acc=0;
  for (int bin=1023;bin>=0;bin--){
    int c=h[bin]; acc+=c;
    if (acc>=K_SELECT){ sel[b*4+0]=bin; sel[b*4+1]=acc-c; break; }
  }
}

__global__ __launch_bounds__(256) void k_hist_fine(const int* __restrict__ smap, const int* __restrict__ sel, int* __restrict__ hist){
  __shared__ int h[1024];
  int tid=threadIdx.x;
  for (int j=tid;j<1024;j+=256) h[j]=0;
  __syncthreads();
  int b=blockIdx.y;
  int cb = sel[b*4+0];
  int base = b*SPATIAL + blockIdx.x*4096;
  #pragma unroll
  for (int e=0;e<16;e++){
    int v = smap[base+e*256+tid];
    if ((v>>10)==cb) atomicAdd(&h[v&1023],1);
  }
  __syncthreads();
  for (int j=tid;j<1024;j+=256){ int c=h[j]; if(c) atomicAdd(&hist[b*1024+j],c); }
}

__global__ void k_select_fine(const int* __restrict__ hist, int* __restrict__ sel){
  int b=blockIdx.x;
  const int* h=hist+b*1024;
  int cb=sel[b*4+0];
  int acc=sel[b*4+1];
  for (int j=1023;j>=0;j--){
    int c=h[j]; acc+=c;
    if (acc>=K_SELECT){ sel[b*4+2]=(cb<<10)|j; sel[b*4+3]=K_SELECT-(acc-c); break; }
  }
}

__global__ __launch_bounds__(256) void k_mask_init(const int* __restrict__ smap, const int* __restrict__ sel,
                                                   float* __restrict__ mask, int* __restrict__ tiecnt, int* __restrict__ tielist){
  int idx = blockIdx.x*256+threadIdx.x;  // < 4194304
  int b = idx>>18;
  int v = smap[idx];
  int T = sel[b*4+2];
  float m = (v>T)?0.f:1.f;
  if (v==T){
    int t = atomicAdd(&tiecnt[b],1);
    if (t<CAP_TIES) tielist[b*CAP_TIES+t] = idx & (SPATIAL-1);
  }
  mask[idx]=m;
}

__global__ __launch_bounds__(256) void k_tie_fix(const int* __restrict__ sel, const int* __restrict__ tiecnt,
                                                 const int* __restrict__ tielist, float* __restrict__ mask){
  int b=blockIdx.x;
  int n = tiecnt[b]; if (n>CAP_TIES) n=CAP_TIES;
  int need = sel[b*4+3];
  for (int e=threadIdx.x; e<n; e+=256){
    int me = tielist[b*CAP_TIES+e];
    int rank=0;
    for (int j=0;j<n;j++) rank += (tielist[b*CAP_TIES+j] < me) ? 1:0;
    if (rank<need) mask[b*SPATIAL+me]=0.f;
  }
}

// pack mask -> bitmask (bit=1 means unknown/masked-out)
__global__ __launch_bounds__(256) void k_mask_bits(const float* __restrict__ mask, uint32_t* __restrict__ bits){
  int i = blockIdx.x*256+threadIdx.x;   // pixel over BATCH*SPATIAL
  float m = mask[i];
  unsigned long long b = __ballot(m==0.f);
  if ((threadIdx.x&63)==0){
    bits[i>>5]     = (uint32_t)(b);
    bits[(i>>5)+1] = (uint32_t)(b>>32);
  }
}

// ---------------- stencil helper ----------------
template<typename F>
__device__ __forceinline__ void stencil_gather(int y,int x,int sp,F val,float& acc,float& sw){
  const float WE=(float)(1.0/6.0), WC=(float)(1.0/12.0);
  acc=0.f; sw=0.f;
  bool ym=y>0, yp=y<HW-1, xm=x>0, xp=x<HW-1;
  if(ym){ sw+=WE; acc+=WE*val(sp-HW);
    if(xm){sw+=WC; acc+=WC*val(sp-HW-1);}
    if(xp){sw+=WC; acc+=WC*val(sp-HW+1);} }
  if(yp){ sw+=WE; acc+=WE*val(sp+HW);
    if(xm){sw+=WC; acc+=WC*val(sp+HW-1);}
    if(xp){sw+=WC; acc+=WC*val(sp+HW+1);} }
  if(xm){ sw+=WE; acc+=WE*val(sp-1); }
  if(xp){ sw+=WE; acc+=WE*val(sp+1); }
}

__device__ __forceinline__ int unk_bit(const uint32_t* bits, int b, int sp){
  return (bits[(b<<13)+(sp>>5)]>>(sp&31))&1;
}

// ---------------- CG kernels ----------------
__global__ __launch_bounds__(256) void k_rhs(const float* __restrict__ img, const float* __restrict__ mask,
                                             h16* __restrict__ r, double* __restrict__ rrp){
  int x = blockIdx.x*64+threadIdx.x;
  int y = blockIdx.y*4+threadIdx.y;
  int bc = blockIdx.z;
  size_t base=(size_t)bc*SPATIAL;
  size_t mb=(size_t)(bc/CH)*SPATIAL;
  int sp=y*HW+x;
  auto val=[&](int j)->float{ return mask[mb+j]*img[base+j]; };
  float acc,sw;
  stencil_gather(y,x,sp,val,acc,sw);
  (void)sw;
  float unk = (mask[mb+sp]==0.f)?1.f:0.f;
  h16 rv = (h16)(unk*acc);
  r[base+sp]=rv;
  float rf=(float)rv;
  int tid=threadIdx.y*64+threadIdx.x;
  double s=wave_block_reduce256((double)rf*(double)rf, tid);
  if (tid==0){
    int slot=(blockIdx.x + blockIdx.y*8 + blockIdx.z*1024)&(NSLOT-1);
    atomicAdd(&rrp[slot], s);
  }
}

// p_new = r + beta*p_old ; Ap on the fly; accumulate p.Ap
__global__ __launch_bounds__(256) void k_pup_apply(const h16* __restrict__ r, const h16* __restrict__ p_old,
    h16* __restrict__ p_new, const uint32_t* __restrict__ bits,
    const double* __restrict__ rrp, double* __restrict__ papp, int iter){
  int x=blockIdx.x*64+threadIdx.x, y=blockIdx.y*4+threadIdx.y, bc=blockIdx.z;
  size_t base=(size_t)bc*SPATIAL;
  int b=bc/CH;
  int sp=y*HW+x;
  float bf=0.f;
  if (iter>0){
    double rprev=0.0, rcur=0.0;
    #pragma unroll
    for(int j=0;j<NSLOT;j++){ rprev+=rrp[(size_t)(iter-1)*NSLOT+j]; rcur+=rrp[(size_t)iter*NSLOT+j]; }
    bf = (rprev>0.0)? (float)(rcur/rprev) : 0.f;
  }
  auto val=[&](int j)->float{
    float v=(float)r[base+j];
    if (iter>0) v += bf*(float)p_old[base+j];
    return v;
  };
  float pc=val(sp);
  float acc,sw; stencil_gather(y,x,sp,val,acc,sw);
  int unk = unk_bit(bits,b,sp);
  float Ap = unk ? (sw*pc-acc) : 0.f;
  p_new[base+sp]=(h16)pc;
  int tid=threadIdx.y*64+threadIdx.x;
  double s=wave_block_reduce256((double)pc*(double)Ap,tid);
  if (tid==0){
    int slot=(blockIdx.x+blockIdx.y*8+blockIdx.z*1024)&(NSLOT-1);
    atomicAdd(&papp[(size_t)iter*NSLOT+slot],s);
  }
}

// x += alpha*p ; r -= alpha*Ap (Ap recomputed from p) ; accumulate r.r
__global__ __launch_bounds__(256) void k_update(float* __restrict__ xv, h16* __restrict__ r,
    const h16* __restrict__ p, const uint32_t* __restrict__ bits,
    double* __restrict__ rrp, const double* __restrict__ papp, int iter){
  int x=blockIdx.x*64+threadIdx.x, y=blockIdx.y*4+threadIdx.y, bc=blockIdx.z;
  size_t base=(size_t)bc*SPATIAL;
  int b=bc/CH;
  int sp=y*HW+x;
  double rcur=0.0, pap=0.0;
  #pragma unroll
  for(int j=0;j<NSLOT;j++){ rcur+=rrp[(size_t)iter*NSLOT+j]; pap+=papp[(size_t)iter*NSLOT+j]; }
  float af = (pap!=0.0)? (float)(rcur/pap) : 0.f;
  size_t i=base+sp;
  float pcv=(float)p[i];
  int unk = unk_bit(bits,b,sp);
  float Ap=0.f;
  if (unk){
    auto val=[&](int j)->float{ return (float)p[base+j]; };
    float acc,sw; stencil_gather(y,x,sp,val,acc,sw);
    Ap=sw*pcv-acc;
  }
  xv[i]+=af*pcv;
  float rn=(float)r[i]-af*Ap;
  r[i]=(h16)rn;
  float rf=(float)((h16)rn);
  int tid=threadIdx.y*64+threadIdx.x;
  double s=wave_block_reduce256((double)rf*(double)rf,tid);
  if (tid==0){
    int slot=(blockIdx.x+blockIdx.y*8+blockIdx.z*1024)&(NSLOT-1);
    atomicAdd(&rrp[(size_t)(iter+1)*NSLOT+slot],s);
  }
}

__global__ __launch_bounds__(256) void k_final(const float* __restrict__ img, const float* __restrict__ noise,
    const float* __restrict__ mask, float* __restrict__ out){
  size_t i=(size_t)blockIdx.x*256+threadIdx.x;
  if (i>=NELEM) return;
  int bc=(int)(i>>18); int sp=(int)(i&(SPATIAL-1));
  size_t mb=(size_t)(bc/CH)<<18;
  float m=mask[mb+sp];
  out[i] = (m!=0.f)? img[i] : out[i] + 0.01f*noise[i];
}

extern "C" void kernel_launch(void* const* d_in, const int* in_sizes, int n_in,
                              void* d_out, int out_size, void* d_ws, size_t ws_size,
                              hipStream_t stream) {
  const float* img  =(const float*)d_in[0];
  const int*   smap =(const int*)d_in[1];
  const float* noise=(const float*)d_in[2];
  float* out=(float*)d_out;
  float* maskout = out + NELEM;          // mask output region (B,H,W)
  char* ws=(char*)d_ws;
  h16* r  =(h16*)(ws+OFF_R);
  h16* pA =(h16*)(ws+OFF_PA);
  h16* pB =(h16*)(ws+OFF_PB);
  uint32_t* bits=(uint32_t*)(ws+OFF_BITS);
  double* rrp =(double*)(ws+OFF_RRP);
  double* papp=(double*)(ws+OFF_PAPP);
  int* hc=(int*)(ws+OFF_HC);
  int* hf=(int*)(ws+OFF_HF);
  int* sel=(int*)(ws+OFF_SEL);
  int* tiecnt=(int*)(ws+OFF_TC);
  int* tielist=(int*)(ws+OFF_TL);

  // zero x (imputed region of d_out) and scalar/hist region
  hipMemsetAsync(out, 0, NELEM*4, stream);
  hipMemsetAsync(ws+OFF_RRP, 0, OFF_TL-OFF_RRP, stream);

  // mask pipeline
  k_hist_coarse<<<dim3(64,16),256,0,stream>>>(smap,hc);
  k_select_coarse<<<16,1,0,stream>>>(hc,sel);
  k_hist_fine<<<dim3(64,16),256,0,stream>>>(smap,sel,hf);
  k_select_fine<<<16,1,0,stream>>>(hf,sel);
  k_mask_init<<<SPATIAL*BATCH/256,256,0,stream>>>(smap,sel,maskout,tiecnt,tielist);
  k_tie_fix<<<16,256,0,stream>>>(sel,tiecnt,tielist,maskout);
  k_mask_bits<<<SPATIAL*BATCH/256,256,0,stream>>>(maskout,bits);

  // rhs -> r ; rr[0]
  dim3 gtile(HW/64, HW/4, NPLANE), btile(64,4);
  k_rhs<<<gtile,btile,0,stream>>>(img,maskout,r,rrp);

  // CG iterations
  for (int i=0;i<NITER;i++){
    h16* pin  = (i&1)? pA : pB;
    h16* pout = (i&1)? pB : pA;
    k_pup_apply<<<gtile,btile,0,stream>>>(r,pin,pout,bits,rrp,papp,i);
    k_update<<<gtile,btile,0,stream>>>(out,r,pout,bits,rrp,papp,i);
  }

  k_final<<<NELEM/256,256,0,stream>>>(img,noise,maskout,out);
}

// Round 3
// 25163.779 us; speedup vs baseline: 1.8029x; 1.5822x over previous
//
#include <hip/hip_runtime.h>
#include <cstdint>
#include <cstddef>

#define HW 512
#define SPATIAL (HW*HW)              // 262144
#define BATCH 16
#define CH 3
#define NPLANE (BATCH*CH)            // 48
#define NELEM ((size_t)NPLANE*SPATIAL) // 12582912
#define K_SELECT 78643
#define NITER 80
#define CAP_TIES 4096
#define NSLOT 64

typedef _Float16 h16;

// workspace layout
static const size_t OFF_R    = 0;                      // h16[NELEM]
static const size_t OFF_PA   = NELEM*2;                // h16[NELEM]
static const size_t OFF_PB   = NELEM*4;                // h16[NELEM]
static const size_t OFF_X    = NELEM*6;                // h16[NELEM]
static const size_t OFF_BITS = NELEM*8;                // uint32[BATCH*8192] = 512KB
static const size_t OFF_RRP  = OFF_BITS + (size_t)BATCH*8192*4;           // double[(NITER+1)*NSLOT]
static const size_t OFF_PAPP = OFF_RRP + (size_t)(NITER+1)*NSLOT*8;       // double[NITER*NSLOT]
static const size_t OFF_HC   = OFF_PAPP + (size_t)NITER*NSLOT*8;          // int[16][1024]
static const size_t OFF_HF   = OFF_HC + (size_t)BATCH*1024*4;             // int[16][1024]
static const size_t OFF_SEL  = OFF_HF + (size_t)BATCH*1024*4;             // int[16][4]
static const size_t OFF_TC   = OFF_SEL + (size_t)BATCH*4*4;               // int[16]
static const size_t OFF_TL   = OFF_TC + 64;                               // int[16][CAP_TIES]

// ---------------- reductions ----------------
__device__ __forceinline__ double wave_block_reduce256(double v, int tid){
  #pragma unroll
  for (int o=32;o>0;o>>=1) v += __shfl_down(v, o, 64);
  __shared__ double sred[4];
  if ((tid & 63)==0) sred[tid>>6] = v;
  __syncthreads();
  double s = 0.0;
  if (tid==0) s = sred[0]+sred[1]+sred[2]+sred[3];
  return s; // valid only on tid 0
}

// scalar broadcast: beta = rr[iter]/rr[iter-1]
__device__ __forceinline__ float load_beta(const double* __restrict__ rrp, int iter, int tid){
  __shared__ float sv;
  if (tid < 64){
    double a = rrp[(size_t)iter*NSLOT + tid];
    double b = (iter>0)? rrp[(size_t)(iter-1)*NSLOT + tid] : 1.0;
    #pragma unroll
    for (int o=32;o>0;o>>=1){ a += __shfl_down(a,o,64); b += __shfl_down(b,o,64); }
    if (tid==0) sv = (iter>0 && b!=0.0)? (float)(a/b) : 0.f;
  }
  __syncthreads();
  return sv;
}

// scalar broadcast: alpha = rr[iter]/pap[iter]
__device__ __forceinline__ float load_alpha(const double* __restrict__ rrp, const double* __restrict__ papp, int iter, int tid){
  __shared__ float sv;
  if (tid < 64){
    double a = rrp[(size_t)iter*NSLOT + tid];
    double b = papp[(size_t)iter*NSLOT + tid];
    #pragma unroll
    for (int o=32;o>0;o>>=1){ a += __shfl_down(a,o,64); b += __shfl_down(b,o,64); }
    if (tid==0) sv = (b!=0.0)? (float)(a/b) : 0.f;
  }
  __syncthreads();
  return sv;
}

// ---------------- mask pipeline ----------------
__global__ __launch_bounds__(256) void k_hist_coarse(const int* __restrict__ smap, int* __restrict__ hist){
  __shared__ int h[1024];
  int tid = threadIdx.x;
  for (int j=tid;j<1024;j+=256) h[j]=0;
  __syncthreads();
  int b = blockIdx.y;
  int base = b*SPATIAL + blockIdx.x*4096;
  #pragma unroll
  for (int e=0;e<16;e++){
    int v = smap[base + e*256 + tid];
    atomicAdd(&h[v>>10], 1);
  }
  __syncthreads();
  for (int j=tid;j<1024;j+=256){ int c=h[j]; if(c) atomicAdd(&hist[b*1024+j], c); }
}

__global__ void k_select_coarse(const int* __restrict__ hist, int* __restrict__ sel){
  int b = blockIdx.x;
  const int* h = hist + b*1024;
  int acc=0;
  for (int bin=1023;bin>=0;bin--){
    int c=h[bin]; acc+=c;
    if (acc>=K_SELECT){ sel[b*4+0]=bin; sel[b*4+1]=acc-c; break; }
  }
}

__global__ __launch_bounds__(256) void k_hist_fine(const int* __restrict__ smap, const int* __restrict__ sel, int* __restrict__ hist){
  __shared__ int h[1024];
  int tid=threadIdx.x;
  for (int j=tid;j<1024;j+=256) h[j]=0;
  __syncthreads();
  int b=blockIdx.y;
  int cb = sel[b*4+0];
  int base = b*SPATIAL + blockIdx.x*4096;
  #pragma unroll
  for (int e=0;e<16;e++){
    int v = smap[base+e*256+tid];
    if ((v>>10)==cb) atomicAdd(&h[v&1023],1);
  }
  __syncthreads();
  for (int j=tid;j<1024;j+=256){ int c=h[j]; if(c) atomicAdd(&hist[b*1024+j],c); }
}

__global__ void k_select_fine(const int* __restrict__ hist, int* __restrict__ sel){
  int b=blockIdx.x;
  const int* h=hist+b*1024;
  int cb=sel[b*4+0];
  int acc=sel[b*4+1];
  for (int j=1023;j>=0;j--){
    int c=h[j]; acc+=c;
    if (acc>=K_SELECT){ sel[b*4+2]=(cb<<10)|j; sel[b*4+3]=K_SELECT-(acc-c); break; }
  }
}

__global__ __launch_bounds__(256) void k_mask_init(const int* __restrict__ smap, const int* __restrict__ sel,
                                                   float* __restrict__ mask, int* __restrict__ tiecnt, int* __restrict__ tielist){
  int idx = blockIdx.x*256+threadIdx.x;  // < 4194304
  int b = idx>>18;
  int v = smap[idx];
  int T = sel[b*4+2];
  float m = (v>T)?0.f:1.f;
  if (v==T){
    int t = atomicAdd(&tiecnt[b],1);
    if (t<CAP_TIES) tielist[b*CAP_TIES+t] = idx & (SPATIAL-1);
  }
  mask[idx]=m;
}

__global__ __launch_bounds__(256) void k_tie_fix(const int* __restrict__ sel, const int* __restrict__ tiecnt,
                                                 const int* __restrict__ tielist, float* __restrict__ mask){
  int b=blockIdx.x;
  int n = tiecnt[b]; if (n>CAP_TIES) n=CAP_TIES;
  int need = sel[b*4+3];
  for (int e=threadIdx.x; e<n; e+=256){
    int me = tielist[b*CAP_TIES+e];
    int rank=0;
    for (int j=0;j<n;j++) rank += (tielist[b*CAP_TIES+j] < me) ? 1:0;
    if (rank<need) mask[b*SPATIAL+me]=0.f;
  }
}

// pack mask -> bitmask (bit=1 means unknown/masked-out)
__global__ __launch_bounds__(256) void k_mask_bits(const float* __restrict__ mask, uint32_t* __restrict__ bits){
  int i = blockIdx.x*256+threadIdx.x;   // pixel over BATCH*SPATIAL
  float m = mask[i];
  unsigned long long b = __ballot(m==0.f);
  if ((threadIdx.x&63)==0){
    bits[i>>5]     = (uint32_t)(b);
    bits[(i>>5)+1] = (uint32_t)(b>>32);
  }
}

// ---------------- stencil helper ----------------
template<typename F>
__device__ __forceinline__ void stencil_gather(int y,int x,int sp,F val,float& acc,float& sw){
  const float WE=(float)(1.0/6.0), WC=(float)(1.0/12.0);
  acc=0.f; sw=0.f;
  bool ym=y>0, yp=y<HW-1, xm=x>0, xp=x<HW-1;
  if(ym){ sw+=WE; acc+=WE*val(sp-HW);
    if(xm){sw+=WC; acc+=WC*val(sp-HW-1);}
    if(xp){sw+=WC; acc+=WC*val(sp-HW+1);} }
  if(yp){ sw+=WE; acc+=WE*val(sp+HW);
    if(xm){sw+=WC; acc+=WC*val(sp+HW-1);}
    if(xp){sw+=WC; acc+=WC*val(sp+HW+1);} }
  if(xm){ sw+=WE; acc+=WE*val(sp-1); }
  if(xp){ sw+=WE; acc+=WE*val(sp+1); }
}

__device__ __forceinline__ int unk_bit(const uint32_t* bits, int b, int sp){
  return (bits[(b<<13)+(sp>>5)]>>(sp&31))&1;
}

// ---------------- CG kernels ----------------
__global__ __launch_bounds__(256) void k_rhs(const float* __restrict__ img, const float* __restrict__ mask,
                                             h16* __restrict__ r, double* __restrict__ rrp){
  int x = blockIdx.x*64+threadIdx.x;
  int y = blockIdx.y*4+threadIdx.y;
  int bc = blockIdx.z;
  size_t base=(size_t)bc*SPATIAL;
  size_t mb=(size_t)(bc/CH)*SPATIAL;
  int sp=y*HW+x;
  auto val=[&](int j)->float{ return mask[mb+j]*img[base+j]; };
  float acc,sw;
  stencil_gather(y,x,sp,val,acc,sw);
  (void)sw;
  float unk = (mask[mb+sp]==0.f)?1.f:0.f;
  h16 rv = (h16)(unk*acc);
  r[base+sp]=rv;
  float rf=(float)rv;
  int tid=threadIdx.y*64+threadIdx.x;
  double s=wave_block_reduce256((double)rf*(double)rf, tid);
  if (tid==0){
    int slot=(blockIdx.x + blockIdx.y*8 + blockIdx.z*1024)&(NSLOT-1);
    atomicAdd(&rrp[slot], s);
  }
}

// p_new = r + beta*p_old ; Ap on the fly; accumulate p.Ap
__global__ __launch_bounds__(256) void k_pup_apply(const h16* __restrict__ r, const h16* __restrict__ p_old,
    h16* __restrict__ p_new, const uint32_t* __restrict__ bits,
    const double* __restrict__ rrp, double* __restrict__ papp, int iter){
  int x=blockIdx.x*64+threadIdx.x, y=blockIdx.y*4+threadIdx.y, bc=blockIdx.z;
  size_t base=(size_t)bc*SPATIAL;
  int b=bc/CH;
  int sp=y*HW+x;
  int tid=threadIdx.y*64+threadIdx.x;
  float bf = load_beta(rrp, iter, tid);
  auto val=[&](int j)->float{
    float v=(float)r[base+j];
    if (iter>0) v += bf*(float)p_old[base+j];
    return v;
  };
  float pc=val(sp);
  float acc,sw; stencil_gather(y,x,sp,val,acc,sw);
  int unk = unk_bit(bits,b,sp);
  float Ap = unk ? (sw*pc-acc) : 0.f;
  p_new[base+sp]=(h16)pc;
  double s=wave_block_reduce256((double)pc*(double)Ap,tid);
  if (tid==0){
    int slot=(blockIdx.x+blockIdx.y*8+blockIdx.z*1024)&(NSLOT-1);
    atomicAdd(&papp[(size_t)iter*NSLOT+slot],s);
  }
}

// x += alpha*p ; r -= alpha*Ap (Ap recomputed from p) ; accumulate r.r
__global__ __launch_bounds__(256) void k_update(h16* __restrict__ xv, h16* __restrict__ r,
    const h16* __restrict__ p, const uint32_t* __restrict__ bits,
    double* __restrict__ rrp, const double* __restrict__ papp, int iter){
  int x=blockIdx.x*64+threadIdx.x, y=blockIdx.y*4+threadIdx.y, bc=blockIdx.z;
  size_t base=(size_t)bc*SPATIAL;
  int b=bc/CH;
  int sp=y*HW+x;
  int tid=threadIdx.y*64+threadIdx.x;
  float af = load_alpha(rrp, papp, iter, tid);
  size_t i=base+sp;
  float pcv=(float)p[i];
  int unk = unk_bit(bits,b,sp);
  float Ap=0.f;
  if (unk){
    auto val=[&](int j)->float{ return (float)p[base+j]; };
    float acc,sw; stencil_gather(y,x,sp,val,acc,sw);
    Ap=sw*pcv-acc;
  }
  xv[i]=(h16)((float)xv[i]+af*pcv);
  float rn=(float)r[i]-af*Ap;
  r[i]=(h16)rn;
  float rf=(float)((h16)rn);
  double s=wave_block_reduce256((double)rf*(double)rf,tid);
  if (tid==0){
    int slot=(blockIdx.x+blockIdx.y*8+blockIdx.z*1024)&(NSLOT-1);
    atomicAdd(&rrp[(size_t)(iter+1)*NSLOT+slot],s);
  }
}

__global__ __launch_bounds__(256) void k_final(const float* __restrict__ img, const float* __restrict__ noise,
    const float* __restrict__ mask, const h16* __restrict__ xv, float* __restrict__ out){
  size_t i=(size_t)blockIdx.x*256+threadIdx.x;
  if (i>=NELEM) return;
  int bc=(int)(i>>18); int sp=(int)(i&(SPATIAL-1));
  size_t mb=(size_t)(bc/CH)<<18;
  float m=mask[mb+sp];
  out[i] = (m!=0.f)? img[i] : (float)xv[i] + 0.01f*noise[i];
}

extern "C" void kernel_launch(void* const* d_in, const int* in_sizes, int n_in,
                              void* d_out, int out_size, void* d_ws, size_t ws_size,
                              hipStream_t stream) {
  const float* img  =(const float*)d_in[0];
  const int*   smap =(const int*)d_in[1];
  const float* noise=(const float*)d_in[2];
  float* out=(float*)d_out;
  float* maskout = out + NELEM;          // mask output region (B,H,W)
  char* ws=(char*)d_ws;
  h16* r  =(h16*)(ws+OFF_R);
  h16* pA =(h16*)(ws+OFF_PA);
  h16* pB =(h16*)(ws+OFF_PB);
  h16* xv =(h16*)(ws+OFF_X);
  uint32_t* bits=(uint32_t*)(ws+OFF_BITS);
  double* rrp =(double*)(ws+OFF_RRP);
  double* papp=(double*)(ws+OFF_PAPP);
  int* hc=(int*)(ws+OFF_HC);
  int* hf=(int*)(ws+OFF_HF);
  int* sel=(int*)(ws+OFF_SEL);
  int* tiecnt=(int*)(ws+OFF_TC);
  int* tielist=(int*)(ws+OFF_TL);

  // zero x, bits, scalars, hists, tiecnt (tielist needs no init)
  hipMemsetAsync(ws+OFF_X, 0, OFF_TL-OFF_X, stream);

  // mask pipeline
  k_hist_coarse<<<dim3(64,16),256,0,stream>>>(smap,hc);
  k_select_coarse<<<16,1,0,stream>>>(hc,sel);
  k_hist_fine<<<dim3(64,16),256,0,stream>>>(smap,sel,hf);
  k_select_fine<<<16,1,0,stream>>>(hf,sel);
  k_mask_init<<<SPATIAL*BATCH/256,256,0,stream>>>(smap,sel,maskout,tiecnt,tielist);
  k_tie_fix<<<16,256,0,stream>>>(sel,tiecnt,tielist,maskout);
  k_mask_bits<<<SPATIAL*BATCH/256,256,0,stream>>>(maskout,bits);

  // rhs -> r ; rr[0]
  dim3 gtile(HW/64, HW/4, NPLANE), btile(64,4);
  k_rhs<<<gtile,btile,0,stream>>>(img,maskout,r,rrp);

  // CG iterations
  for (int i=0;i<NITER;i++){
    h16* pin  = (i&1)? pA : pB;
    h16* pout = (i&1)? pB : pA;
    k_pup_apply<<<gtile,btile,0,stream>>>(r,pin,pout,bits,rrp,papp,i);
    k_update<<<gtile,btile,0,stream>>>(xv,r,pout,bits,rrp,papp,i);
  }

  k_final<<<NELEM/256,256,0,stream>>>(img,noise,maskout,xv,out);
}

// Round 4
// 2281.588 us; speedup vs baseline: 19.8846x; 11.0291x over previous
//
#include <hip/hip_runtime.h>
#include <cstdint>
#include <cstddef>

#define HW 512
#define SPATIAL (HW*HW)              // 262144
#define BATCH 16
#define CH 3
#define NPLANE (BATCH*CH)            // 48
#define NELEM ((size_t)NPLANE*SPATIAL) // 12582912
#define K_SELECT 78643
#define NITER 48
#define CAP_TIES 4096
#define NSLOT 64
#define PAD 8   // doubles per slot -> one 64B line per slot

typedef _Float16 h16;
typedef __attribute__((ext_vector_type(8))) _Float16 h16x8;  // 16B
typedef __attribute__((ext_vector_type(8))) float f32x8;     // 32B

// workspace layout
static const size_t OFF_R    = 0;                      // h16[NELEM]
static const size_t OFF_PA   = NELEM*2;                // h16[NELEM]
static const size_t OFF_PB   = NELEM*4;                // h16[NELEM]
static const size_t OFF_X    = NELEM*6;                // h16[NELEM]
static const size_t OFF_BITS = NELEM*8;                // uint32[BATCH*8192] = 512KB
static const size_t OFF_RRP  = OFF_BITS + (size_t)BATCH*8192*4;             // double[(NITER+1)*NSLOT*PAD]
static const size_t OFF_PAPP = OFF_RRP + (size_t)(NITER+1)*NSLOT*PAD*8;     // double[NITER*NSLOT*PAD]
static const size_t OFF_HC   = OFF_PAPP + (size_t)NITER*NSLOT*PAD*8;        // int[16][1024]
static const size_t OFF_HF   = OFF_HC + (size_t)BATCH*1024*4;               // int[16][1024]
static const size_t OFF_SEL  = OFF_HF + (size_t)BATCH*1024*4;               // int[16][4]
static const size_t OFF_TC   = OFF_SEL + (size_t)BATCH*4*4;                 // int[16]
static const size_t OFF_TL   = OFF_TC + 64;                                 // int[16][CAP_TIES]

// ---------------- reductions ----------------
__device__ __forceinline__ double wave_block_reduce256(double v, int tid){
  #pragma unroll
  for (int o=32;o>0;o>>=1) v += __shfl_down(v, o, 64);
  __shared__ double sred[4];
  if ((tid & 63)==0) sred[tid>>6] = v;
  __syncthreads();
  double s = 0.0;
  if (tid==0) s = sred[0]+sred[1]+sred[2]+sred[3];
  return s; // valid only on tid 0
}

__device__ __forceinline__ float load_beta(const double* __restrict__ rrp, int iter, int tid){
  __shared__ float sv;
  if (tid < 64){
    double a = rrp[((size_t)iter*NSLOT + tid)*PAD];
    double b = (iter>0)? rrp[((size_t)(iter-1)*NSLOT + tid)*PAD] : 1.0;
    #pragma unroll
    for (int o=32;o>0;o>>=1){ a += __shfl_down(a,o,64); b += __shfl_down(b,o,64); }
    if (tid==0) sv = (iter>0 && b!=0.0)? (float)(a/b) : 0.f;
  }
  __syncthreads();
  return sv;
}

__device__ __forceinline__ float load_alpha(const double* __restrict__ rrp, const double* __restrict__ papp, int iter, int tid){
  __shared__ float sv;
  if (tid < 64){
    double a = rrp[((size_t)iter*NSLOT + tid)*PAD];
    double b = papp[((size_t)iter*NSLOT + tid)*PAD];
    #pragma unroll
    for (int o=32;o>0;o>>=1){ a += __shfl_down(a,o,64); b += __shfl_down(b,o,64); }
    if (tid==0) sv = (b!=0.0)? (float)(a/b) : 0.f;
  }
  __syncthreads();
  return sv;
}

// ---------------- mask pipeline ----------------
__global__ __launch_bounds__(256) void k_hist_coarse(const int* __restrict__ smap, int* __restrict__ hist){
  __shared__ int h[1024];
  int tid = threadIdx.x;
  for (int j=tid;j<1024;j+=256) h[j]=0;
  __syncthreads();
  int b = blockIdx.y;
  int base = b*SPATIAL + blockIdx.x*4096;
  #pragma unroll
  for (int e=0;e<16;e++){
    int v = smap[base + e*256 + tid];
    atomicAdd(&h[v>>10], 1);
  }
  __syncthreads();
  for (int j=tid;j<1024;j+=256){ int c=h[j]; if(c) atomicAdd(&hist[b*1024+j], c); }
}

__global__ void k_select_coarse(const int* __restrict__ hist, int* __restrict__ sel){
  int b = blockIdx.x;
  const int* h = hist + b*1024;
  int acc=0;
  for (int bin=1023;bin>=0;bin--){
    int c=h[bin]; acc+=c;
    if (acc>=K_SELECT){ sel[b*4+0]=bin; sel[b*4+1]=acc-c; break; }
  }
}

__global__ __launch_bounds__(256) void k_hist_fine(const int* __restrict__ smap, const int* __restrict__ sel, int* __restrict__ hist){
  __shared__ int h[1024];
  int tid=threadIdx.x;
  for (int j=tid;j<1024;j+=256) h[j]=0;
  __syncthreads();
  int b=blockIdx.y;
  int cb = sel[b*4+0];
  int base = b*SPATIAL + blockIdx.x*4096;
  #pragma unroll
  for (int e=0;e<16;e++){
    int v = smap[base+e*256+tid];
    if ((v>>10)==cb) atomicAdd(&h[v&1023],1);
  }
  __syncthreads();
  for (int j=tid;j<1024;j+=256){ int c=h[j]; if(c) atomicAdd(&hist[b*1024+j],c); }
}

__global__ void k_select_fine(const int* __restrict__ hist, int* __restrict__ sel){
  int b=blockIdx.x;
  const int* h=hist+b*1024;
  int cb=sel[b*4+0];
  int acc=sel[b*4+1];
  for (int j=1023;j>=0;j--){
    int c=h[j]; acc+=c;
    if (acc>=K_SELECT){ sel[b*4+2]=(cb<<10)|j; sel[b*4+3]=K_SELECT-(acc-c); break; }
  }
}

__global__ __launch_bounds__(256) void k_mask_init(const int* __restrict__ smap, const int* __restrict__ sel,
                                                   float* __restrict__ mask, int* __restrict__ tiecnt, int* __restrict__ tielist){
  int idx = blockIdx.x*256+threadIdx.x;  // < 4194304
  int b = idx>>18;
  int v = smap[idx];
  int T = sel[b*4+2];
  float m = (v>T)?0.f:1.f;
  if (v==T){
    int t = atomicAdd(&tiecnt[b],1);
    if (t<CAP_TIES) tielist[b*CAP_TIES+t] = idx & (SPATIAL-1);
  }
  mask[idx]=m;
}

__global__ __launch_bounds__(256) void k_tie_fix(const int* __restrict__ sel, const int* __restrict__ tiecnt,
                                                 const int* __restrict__ tielist, float* __restrict__ mask){
  int b=blockIdx.x;
  int n = tiecnt[b]; if (n>CAP_TIES) n=CAP_TIES;
  int need = sel[b*4+3];
  for (int e=threadIdx.x; e<n; e+=256){
    int me = tielist[b*CAP_TIES+e];
    int rank=0;
    for (int j=0;j<n;j++) rank += (tielist[b*CAP_TIES+j] < me) ? 1:0;
    if (rank<need) mask[b*SPATIAL+me]=0.f;
  }
}

// pack mask -> bitmask (bit=1 means unknown/masked-out)
__global__ __launch_bounds__(256) void k_mask_bits(const float* __restrict__ mask, uint32_t* __restrict__ bits){
  int i = blockIdx.x*256+threadIdx.x;   // pixel over BATCH*SPATIAL
  float m = mask[i];
  unsigned long long b = __ballot(m==0.f);
  if ((threadIdx.x&63)==0){
    bits[i>>5]     = (uint32_t)(b);
    bits[(i>>5)+1] = (uint32_t)(b>>32);
  }
}

// ---------------- window helper: 8 px per lane + halo via shuffles ----------------
__device__ __forceinline__ void build_win(const float v[8], float w[10], int lane){
  float up = __shfl_up(v[7], 1, 64);
  float dn = __shfl_down(v[0], 1, 64);
  w[0] = (lane==0)? 0.f : up;
  #pragma unroll
  for (int e=0;e<8;e++) w[e+1]=v[e];
  w[9] = (lane==63)? 0.f : dn;
}

#define GEOM() \
  int lane = threadIdx.x; \
  int y = blockIdx.x*4 + threadIdx.y; \
  int bc = blockIdx.y; \
  int b = bc/CH; \
  size_t base = (size_t)bc*SPATIAL; \
  int x0 = lane*8; \
  int sp0 = y*HW + x0; \
  int tid = threadIdx.y*64 + lane; \
  bool ym = (y>0), yp = (y<HW-1); \
  float fym = ym?1.f:0.f, fyp = yp?1.f:0.f;

#define STENCIL_E(e, pc, accv, swv) \
  int xg = x0+e; \
  float xmf = (xg>0)?1.f:0.f, xpf = (xg<HW-1)?1.f:0.f; \
  float pc = w0[e+1]; \
  float accv = WE*(wm1[e+1]+wp1[e+1]+w0[e]+w0[e+2]) \
             + WC*(wm1[e]+wm1[e+2]+wp1[e]+wp1[e+2]); \
  float swv = WE*(fym+fyp+xmf+xpf) + WC*(fym*xmf+fym*xpf+fyp*xmf+fyp*xpf);

// ---------------- CG kernels ----------------
__global__ __launch_bounds__(256) void k_rhs(const float* __restrict__ img, const float* __restrict__ mask,
                                             const uint32_t* __restrict__ bits, h16* __restrict__ r,
                                             double* __restrict__ rrp){
  GEOM();
  const float* ib = img + base;
  const float* mb = mask + (size_t)b*SPATIAL;
  int om1 = ym? sp0-HW : sp0;
  int op1 = yp? sp0+HW : sp0;
  f32x8 im1 = *(const f32x8*)(ib+om1), i0 = *(const f32x8*)(ib+sp0), ip1 = *(const f32x8*)(ib+op1);
  f32x8 mm1 = *(const f32x8*)(mb+om1), m0 = *(const f32x8*)(mb+sp0), mp1 = *(const f32x8*)(mb+op1);
  float vm1[8], v0[8], vp1[8];
  #pragma unroll
  for (int e=0;e<8;e++){
    vm1[e] = ym? mm1[e]*im1[e] : 0.f;
    v0[e]  = m0[e]*i0[e];
    vp1[e] = yp? mp1[e]*ip1[e] : 0.f;
  }
  float wm1[10], w0[10], wp1[10];
  build_win(vm1,wm1,lane); build_win(v0,w0,lane); build_win(vp1,wp1,lane);
  uint32_t wb = bits[((size_t)b<<13)+(sp0>>5)];
  int bit0 = sp0 & 31;
  const float WE=1.f/6.f, WC=1.f/12.f;
  h16x8 ro;
  double dot=0.0;
  #pragma unroll
  for (int e=0;e<8;e++){
    STENCIL_E(e, pc, accv, swv);
    (void)pc; (void)swv;
    float rv = ((wb>>(bit0+e))&1) ? accv : 0.f;
    h16 rh = (h16)rv;
    ro[e]=rh;
    float rf=(float)rh;
    dot += (double)rf*(double)rf;
  }
  *(h16x8*)(r+base+sp0) = ro;
  double s = wave_block_reduce256(dot, tid);
  if (tid==0){
    int slot=(blockIdx.x + blockIdx.y*131)&(NSLOT-1);
    atomicAdd(&rrp[(size_t)slot*PAD], s);
  }
}

// p_new = r + beta*p_old ; Ap on the fly; accumulate p.Ap
__global__ __launch_bounds__(256) void k_pup_apply(const h16* __restrict__ r, const h16* __restrict__ p_old,
    h16* __restrict__ p_new, const uint32_t* __restrict__ bits,
    const double* __restrict__ rrp, double* __restrict__ papp, int iter){
  GEOM();
  float bf = load_beta(rrp, iter, tid);
  const h16* rb = r + base;
  const h16* pb = p_old + base;
  int om1 = ym? sp0-HW : sp0;
  int op1 = yp? sp0+HW : sp0;
  h16x8 am1 = *(const h16x8*)(rb+om1), a0 = *(const h16x8*)(rb+sp0), ap1 = *(const h16x8*)(rb+op1);
  float vm1[8], v0[8], vp1[8];
  if (iter>0){
    h16x8 qm1 = *(const h16x8*)(pb+om1), q0 = *(const h16x8*)(pb+sp0), qp1 = *(const h16x8*)(pb+op1);
    #pragma unroll
    for (int e=0;e<8;e++){
      vm1[e] = ym? ((float)am1[e] + bf*(float)qm1[e]) : 0.f;
      v0[e]  = (float)a0[e]  + bf*(float)q0[e];
      vp1[e] = yp? ((float)ap1[e] + bf*(float)qp1[e]) : 0.f;
    }
  } else {
    #pragma unroll
    for (int e=0;e<8;e++){
      vm1[e] = ym? (float)am1[e] : 0.f;
      v0[e]  = (float)a0[e];
      vp1[e] = yp? (float)ap1[e] : 0.f;
    }
  }
  float wm1[10], w0[10], wp1[10];
  build_win(vm1,wm1,lane); build_win(v0,w0,lane); build_win(vp1,wp1,lane);
  uint32_t wb = bits[((size_t)b<<13)+(sp0>>5)];
  int bit0 = sp0 & 31;
  const float WE=1.f/6.f, WC=1.f/12.f;
  h16x8 po;
  double dot=0.0;
  #pragma unroll
  for (int e=0;e<8;e++){
    STENCIL_E(e, pc, accv, swv);
    float Ap = ((wb>>(bit0+e))&1) ? (swv*pc-accv) : 0.f;
    po[e]=(h16)pc;
    dot += (double)pc*(double)Ap;
  }
  *(h16x8*)(p_new+base+sp0) = po;
  double s = wave_block_reduce256(dot, tid);
  if (tid==0){
    int slot=(blockIdx.x + blockIdx.y*131)&(NSLOT-1);
    atomicAdd(&papp[((size_t)iter*NSLOT+slot)*PAD], s);
  }
}

// x += alpha*p ; r -= alpha*Ap (Ap recomputed from p) ; accumulate r.r
__global__ __launch_bounds__(256) void k_update(h16* __restrict__ xv, h16* __restrict__ r,
    const h16* __restrict__ p, const uint32_t* __restrict__ bits,
    double* __restrict__ rrp, const double* __restrict__ papp, int iter){
  GEOM();
  float af = load_alpha(rrp, papp, iter, tid);
  const h16* pb = p + base;
  int om1 = ym? sp0-HW : sp0;
  int op1 = yp? sp0+HW : sp0;
  h16x8 qm1 = *(const h16x8*)(pb+om1), q0 = *(const h16x8*)(pb+sp0), qp1 = *(const h16x8*)(pb+op1);
  float vm1[8], v0[8], vp1[8];
  #pragma unroll
  for (int e=0;e<8;e++){
    vm1[e] = ym? (float)qm1[e] : 0.f;
    v0[e]  = (float)q0[e];
    vp1[e] = yp? (float)qp1[e] : 0.f;
  }
  float wm1[10], w0[10], wp1[10];
  build_win(vm1,wm1,lane); build_win(v0,w0,lane); build_win(vp1,wp1,lane);
  uint32_t wb = bits[((size_t)b<<13)+(sp0>>5)];
  int bit0 = sp0 & 31;
  const float WE=1.f/6.f, WC=1.f/12.f;
  h16x8 xc = *(const h16x8*)(xv+base+sp0);
  h16x8 rc = *(const h16x8*)(r+base+sp0);
  h16x8 xo, ro;
  double dot=0.0;
  #pragma unroll
  for (int e=0;e<8;e++){
    STENCIL_E(e, pc, accv, swv);
    float Ap = ((wb>>(bit0+e))&1) ? (swv*pc-accv) : 0.f;
    xo[e] = (h16)((float)xc[e] + af*pc);
    h16 rh = (h16)((float)rc[e] - af*Ap);
    ro[e] = rh;
    float rf = (float)rh;
    dot += (double)rf*(double)rf;
  }
  *(h16x8*)(xv+base+sp0) = xo;
  *(h16x8*)(r+base+sp0) = ro;
  double s = wave_block_reduce256(dot, tid);
  if (tid==0){
    int slot=(blockIdx.x + blockIdx.y*131)&(NSLOT-1);
    atomicAdd(&rrp[((size_t)(iter+1)*NSLOT+slot)*PAD], s);
  }
}

__global__ __launch_bounds__(256) void k_final(const float* __restrict__ img, const float* __restrict__ noise,
    const uint32_t* __restrict__ bits, const h16* __restrict__ xv, float* __restrict__ out){
  GEOM();
  (void)fym; (void)fyp;
  f32x8 iv = *(const f32x8*)(img+base+sp0);
  f32x8 nv = *(const f32x8*)(noise+base+sp0);
  h16x8 xc = *(const h16x8*)(xv+base+sp0);
  uint32_t wb = bits[((size_t)b<<13)+(sp0>>5)];
  int bit0 = sp0 & 31;
  f32x8 ov;
  #pragma unroll
  for (int e=0;e<8;e++){
    ov[e] = ((wb>>(bit0+e))&1) ? ((float)xc[e] + 0.01f*nv[e]) : iv[e];
  }
  *(f32x8*)(out+base+sp0) = ov;
}

extern "C" void kernel_launch(void* const* d_in, const int* in_sizes, int n_in,
                              void* d_out, int out_size, void* d_ws, size_t ws_size,
                              hipStream_t stream) {
  const float* img  =(const float*)d_in[0];
  const int*   smap =(const int*)d_in[1];
  const float* noise=(const float*)d_in[2];
  float* out=(float*)d_out;
  float* maskout = out + NELEM;          // mask output region (B,H,W)
  char* ws=(char*)d_ws;
  h16* r  =(h16*)(ws+OFF_R);
  h16* pA =(h16*)(ws+OFF_PA);
  h16* pB =(h16*)(ws+OFF_PB);
  h16* xv =(h16*)(ws+OFF_X);
  uint32_t* bits=(uint32_t*)(ws+OFF_BITS);
  double* rrp =(double*)(ws+OFF_RRP);
  double* papp=(double*)(ws+OFF_PAPP);
  int* hc=(int*)(ws+OFF_HC);
  int* hf=(int*)(ws+OFF_HF);
  int* sel=(int*)(ws+OFF_SEL);
  int* tiecnt=(int*)(ws+OFF_TC);
  int* tielist=(int*)(ws+OFF_TL);

  // zero x, bits, scalars, hists, sel, tiecnt (tielist guarded by tiecnt)
  hipMemsetAsync(ws+OFF_X, 0, OFF_TL-OFF_X, stream);

  // mask pipeline
  k_hist_coarse<<<dim3(64,16),256,0,stream>>>(smap,hc);
  k_select_coarse<<<16,1,0,stream>>>(hc,sel);
  k_hist_fine<<<dim3(64,16),256,0,stream>>>(smap,sel,hf);
  k_select_fine<<<16,1,0,stream>>>(hf,sel);
  k_mask_init<<<SPATIAL*BATCH/256,256,0,stream>>>(smap,sel,maskout,tiecnt,tielist);
  k_tie_fix<<<16,256,0,stream>>>(sel,tiecnt,tielist,maskout);
  k_mask_bits<<<SPATIAL*BATCH/256,256,0,stream>>>(maskout,bits);

  dim3 g(HW/4, NPLANE), blk(64,4);
  k_rhs<<<g,blk,0,stream>>>(img,maskout,bits,r,rrp);

  for (int i=0;i<NITER;i++){
    h16* pin  = (i&1)? pA : pB;
    h16* pout = (i&1)? pB : pA;
    k_pup_apply<<<g,blk,0,stream>>>(r,pin,pout,bits,rrp,papp,i);
    k_update<<<g,blk,0,stream>>>(xv,r,pout,bits,rrp,papp,i);
  }

  k_final<<<g,blk,0,stream>>>(img,noise,bits,xv,out);
}

// Round 5
// 2176.212 us; speedup vs baseline: 20.8475x; 1.0484x over previous
//
#include <hip/hip_runtime.h>
#include <cstdint>
#include <cstddef>

#define HW 512
#define SPATIAL (HW*HW)              // 262144
#define BATCH 16
#define CH 3
#define NPLANE (BATCH*CH)            // 48
#define NELEM ((size_t)NPLANE*SPATIAL) // 12582912
#define K_SELECT 78643
#define NITER 48
#define CAP_TIES 4096
#define NSLOT 64
#define PAD 8     // doubles per slot -> one 64B line per slot
#define BAND 8    // rows per wave in CG kernels

typedef _Float16 h16;
typedef __attribute__((ext_vector_type(8))) _Float16 h16x8;  // 16B
typedef __attribute__((ext_vector_type(8))) float f32x8;     // 32B

// workspace layout
static const size_t OFF_RA   = 0;                      // h16[NELEM]
static const size_t OFF_RB   = NELEM*2;                // h16[NELEM]
static const size_t OFF_PA   = NELEM*4;                // h16[NELEM]
static const size_t OFF_PB   = NELEM*6;                // h16[NELEM]
static const size_t OFF_BITS = NELEM*8;                // uint32[BATCH*8192] = 512KB (fully written, no memset)
static const size_t OFF_X    = OFF_BITS + (size_t)BATCH*8192*4;   // h16[NELEM]  <- memset starts here
static const size_t OFF_DOTS = OFF_X + NELEM*2;        // double[(NITER+1)*3*NSLOT*PAD]
static const size_t OFF_HC   = OFF_DOTS + (size_t)(NITER+1)*3*NSLOT*PAD*8;
static const size_t OFF_HF   = OFF_HC + (size_t)BATCH*1024*4;
static const size_t OFF_SEL  = OFF_HF + (size_t)BATCH*1024*4;     // int[16][4]
static const size_t OFF_TC   = OFF_SEL + (size_t)BATCH*4*4;       // int[16]
static const size_t OFF_TL   = OFF_TC + 64;                       // int[16][CAP_TIES]

// ---------------- mask pipeline ----------------
__global__ __launch_bounds__(256) void k_hist_coarse(const int* __restrict__ smap, int* __restrict__ hist){
  __shared__ int h[1024];
  int tid = threadIdx.x;
  for (int j=tid;j<1024;j+=256) h[j]=0;
  __syncthreads();
  int b = blockIdx.y;
  int base = b*SPATIAL + blockIdx.x*4096;
  #pragma unroll
  for (int e=0;e<16;e++){
    int v = smap[base + e*256 + tid];
    atomicAdd(&h[v>>10], 1);
  }
  __syncthreads();
  for (int j=tid;j<1024;j+=256){ int c=h[j]; if(c) atomicAdd(&hist[b*1024+j], c); }
}

// one wave per batch: suffix-scan over 64 lanes x 16 bins
__global__ __launch_bounds__(1024) void k_select_coarse(const int* __restrict__ hist, int* __restrict__ sel){
  int lane = threadIdx.x, b = threadIdx.y;
  const int* h = hist + b*1024;
  int loc[16]; int s=0;
  #pragma unroll
  for (int j=0;j<16;j++){ loc[j]=h[lane*16+j]; s+=loc[j]; }
  int T=s;
  #pragma unroll
  for (int o=1;o<64;o<<=1){ int t=__shfl_down(T,o,64); if (lane+o<64) T+=t; }
  int S = T - s;  // sum over lanes > lane
  if (S < K_SELECT && T >= K_SELECT){
    int acc=S;
    #pragma unroll
    for (int j=15;j>=0;j--){
      acc+=loc[j];
      if (acc>=K_SELECT){ sel[b*4+0]=lane*16+j; sel[b*4+1]=acc-loc[j]; break; }
    }
  }
}

__global__ __launch_bounds__(256) void k_hist_fine(const int* __restrict__ smap, const int* __restrict__ sel, int* __restrict__ hist){
  __shared__ int h[1024];
  int tid=threadIdx.x;
  for (int j=tid;j<1024;j+=256) h[j]=0;
  __syncthreads();
  int b=blockIdx.y;
  int cb = sel[b*4+0];
  int base = b*SPATIAL + blockIdx.x*4096;
  #pragma unroll
  for (int e=0;e<16;e++){
    int v = smap[base+e*256+tid];
    if ((v>>10)==cb) atomicAdd(&h[v&1023],1);
  }
  __syncthreads();
  for (int j=tid;j<1024;j+=256){ int c=h[j]; if(c) atomicAdd(&hist[b*1024+j],c); }
}

__global__ __launch_bounds__(1024) void k_select_fine(const int* __restrict__ hist, int* __restrict__ sel){
  int lane = threadIdx.x, b = threadIdx.y;
  const int* h = hist + b*1024;
  int cb = sel[b*4+0];
  int acc0 = sel[b*4+1];
  int loc[16]; int s=0;
  #pragma unroll
  for (int j=0;j<16;j++){ loc[j]=h[lane*16+j]; s+=loc[j]; }
  int T=s;
  #pragma unroll
  for (int o=1;o<64;o<<=1){ int t=__shfl_down(T,o,64); if (lane+o<64) T+=t; }
  int S = acc0 + (T - s);
  int Ti = acc0 + T;
  if (S < K_SELECT && Ti >= K_SELECT){
    int acc=S;
    #pragma unroll
    for (int j=15;j>=0;j--){
      acc+=loc[j];
      if (acc>=K_SELECT){
        sel[b*4+2]=(cb<<10)|(lane*16+j);
        sel[b*4+3]=K_SELECT-(acc-loc[j]);
        break;
      }
    }
  }
}

// mask + bit-pack (bit=1 means unknown) in one pass
__global__ __launch_bounds__(256) void k_mask_init(const int* __restrict__ smap, const int* __restrict__ sel,
                                                   float* __restrict__ mask, uint32_t* __restrict__ bits,
                                                   int* __restrict__ tiecnt, int* __restrict__ tielist){
  int idx = blockIdx.x*256+threadIdx.x;  // < 4194304
  int b = idx>>18;
  int v = smap[idx];
  int T = sel[b*4+2];
  bool unk = (v>T);
  unsigned long long bal = __ballot(unk);
  if ((threadIdx.x&63)==0){
    bits[idx>>5]     = (uint32_t)(bal);
    bits[(idx>>5)+1] = (uint32_t)(bal>>32);
  }
  if (v==T){
    int t = atomicAdd(&tiecnt[b],1);
    if (t<CAP_TIES) tielist[b*CAP_TIES+t] = idx & (SPATIAL-1);
  }
  mask[idx]= unk? 0.f : 1.f;
}

__global__ __launch_bounds__(256) void k_tie_fix(const int* __restrict__ sel, const int* __restrict__ tiecnt,
                                                 const int* __restrict__ tielist, float* __restrict__ mask,
                                                 uint32_t* __restrict__ bits){
  int b=blockIdx.x;
  int n = tiecnt[b]; if (n>CAP_TIES) n=CAP_TIES;
  int need = sel[b*4+3];
  for (int e=threadIdx.x; e<n; e+=256){
    int me = tielist[b*CAP_TIES+e];
    int rank=0;
    for (int j=0;j<n;j++) rank += (tielist[b*CAP_TIES+j] < me) ? 1:0;
    if (rank<need){
      mask[b*SPATIAL+me]=0.f;
      atomicOr(&bits[(b<<13)+(me>>5)], 1u<<(me&31));
    }
  }
}

// ---------------- stencil helpers ----------------
__device__ __forceinline__ void bwin(const float v[8], float w[10], int lane){
  float up = __shfl_up(v[7],1,64);
  float dn = __shfl_down(v[0],1,64);
  w[0] = (lane==0)?0.f:up;
  #pragma unroll
  for(int e=0;e<8;e++) w[e+1]=v[e];
  w[9] = (lane==63)?0.f:dn;
}
__device__ __forceinline__ float accE(const float* wm, const float* wc, const float* wp, int e){
  const float WE=1.f/6.f, WC=1.f/12.f;
  return WE*(wm[e+1]+wp[e+1]+wc[e]+wc[e+2]) + WC*(wm[e]+wm[e+2]+wp[e]+wp[e+2]);
}
__device__ __forceinline__ float swE(int y,int xg){
  const float WE=1.f/6.f, WC=1.f/12.f;
  float fym=(y>0)?1.f:0.f, fyp=(y<HW-1)?1.f:0.f;
  float xmf=(xg>0)?1.f:0.f, xpf=(xg<HW-1)?1.f:0.f;
  return WE*(fym+fyp+xmf+xpf) + WC*(fym*xmf+fym*xpf+fyp*xmf+fyp*xpf);
}
__device__ __forceinline__ void loadh(const h16* buf, int y, int x0, float v[8]){
  if ((unsigned)y < HW){
    h16x8 t = *(const h16x8*)(buf + y*HW + x0);
    #pragma unroll
    for (int e=0;e<8;e++) v[e]=(float)t[e];
  } else {
    #pragma unroll
    for (int e=0;e<8;e++) v[e]=0.f;
  }
}

// 3-dot block reduce + atomic emit into slot arrays
__device__ __forceinline__ void dots_emit(double a,double b,double c,int tid,double* dst,int it){
  #pragma unroll
  for (int o=32;o>0;o>>=1){ a+=__shfl_down(a,o,64); b+=__shfl_down(b,o,64); c+=__shfl_down(c,o,64); }
  __shared__ double s3[3][4];
  int wv = tid>>6;
  if ((tid&63)==0){ s3[0][wv]=a; s3[1][wv]=b; s3[2][wv]=c; }
  __syncthreads();
  if (tid==0){
    double A=s3[0][0]+s3[0][1]+s3[0][2]+s3[0][3];
    double B=s3[1][0]+s3[1][1]+s3[1][2]+s3[1][3];
    double C=s3[2][0]+s3[2][1]+s3[2][2]+s3[2][3];
    int slot = blockIdx.x & (NSLOT-1);
    atomicAdd(&dst[(((size_t)it*3+0)*NSLOT+slot)*PAD], A);
    atomicAdd(&dst[(((size_t)it*3+1)*NSLOT+slot)*PAD], B);
    atomicAdd(&dst[(((size_t)it*3+2)*NSLOT+slot)*PAD], C);
  }
}

// ---------------- rhs: r0 = p0 = unk*stencil(m*img); dots pAp0, ApAp0, rr0 ----------------
__global__ __launch_bounds__(256) void k_rhs(const float* __restrict__ img, const uint32_t* __restrict__ bits,
                                             h16* __restrict__ r0, double* __restrict__ dots){
  int lane=threadIdx.x; int tid=threadIdx.y*64+lane;
  int w = blockIdx.x*4+threadIdx.y;
  int plane = w>>6; int a = (w&63)*BAND;
  const float* ip = img + (size_t)plane*SPATIAL;
  h16* rn = r0 + (size_t)plane*SPATIAL;
  const uint32_t* ub = bits + ((size_t)(plane/CH)<<13);
  int x0=lane*8, wofs=lane>>2, bit0=(lane&3)*8;
  float wv_m[10], wv_c[10], wv_p[10], wr_2[10], wr_1[10], wr_0[10];
  float t[8];
  // v(y) = known? img : 0
  auto loadv=[&](int y, float v[8]){
    if ((unsigned)y < HW){
      f32x8 iv = *(const f32x8*)(ip + y*HW + x0);
      uint32_t uy = ub[y*16 + wofs];
      #pragma unroll
      for (int e=0;e<8;e++) v[e] = ((uy>>(bit0+e))&1u)? 0.f : iv[e];
    } else {
      #pragma unroll
      for (int e=0;e<8;e++) v[e]=0.f;
    }
  };
  loadv(a-2,t); bwin(t,wv_m,lane);
  loadv(a-1,t); bwin(t,wv_c,lane);
  #pragma unroll
  for (int j=0;j<10;j++){ wr_2[j]=0.f; wr_1[j]=0.f; }
  uint32_t ub_1=0;
  double d_pap=0.0, d_apap=0.0, d_rr=0.0;
  for (int y=a-1; y<=a+BAND; ++y){
    loadv(y+1,t); bwin(t,wv_p,lane);
    uint32_t uy = ((unsigned)y<HW)? ub[y*16+wofs] : 0u;
    float rr8[8];
    #pragma unroll
    for (int e=0;e<8;e++){
      float rv = ((uy>>(bit0+e))&1u)? accE(wv_m,wv_c,wv_p,e) : 0.f;
      rr8[e] = (float)(h16)rv;   // store-rounded value everywhere for consistency
    }
    if (y>=a && y<a+BAND){
      h16x8 rw;
      #pragma unroll
      for (int e=0;e<8;e++){ rw[e]=(h16)rr8[e]; d_rr += (double)rr8[e]*(double)rr8[e]; }
      *(h16x8*)(rn + y*HW + x0) = rw;
    }
    bwin(rr8, wr_0, lane);
    if (y-1>=a && y-1<a+BAND){
      #pragma unroll
      for (int e=0;e<8;e++){
        float unk = (float)((ub_1>>(bit0+e))&1u);
        float Ap = unk * (swE(y-1,x0+e)*wr_1[e+1] - accE(wr_2,wr_1,wr_0,e));
        d_pap += (double)wr_1[e+1]*(double)Ap;
        d_apap+= (double)Ap*(double)Ap;
      }
    }
    #pragma unroll
    for (int j=0;j<10;j++){ wv_m[j]=wv_c[j]; wv_c[j]=wv_p[j]; wr_2[j]=wr_1[j]; wr_1[j]=wr_0[j]; }
    ub_1 = uy;
  }
  dots_emit(d_pap,d_apap,d_rr,tid,dots,0);
}

// ---------------- merged CG iteration ----------------
// K(i): alpha_{i-1}=rr_{i-1}/pAp_{i-1}; rr_i^rec = a^2*ApAp_{i-1} - rr_{i-1}; beta_i = rr_i^rec/rr_{i-1}
//   x_i = x_{i-1} + a*p_{i-1};  r_i = r_{i-1} - a*A p_{i-1};  p_i = r_i + b*p_{i-1}
//   dots: pAp_i, ApAp_i, rr_i(direct)
__global__ __launch_bounds__(256) void k_cg(const h16* rprev, h16* __restrict__ rnext,
    const h16* pprev, h16* __restrict__ pnext, h16* __restrict__ xv,
    const uint32_t* __restrict__ bits, double* __restrict__ dots, int iter, int last){
  int lane = threadIdx.x;
  int tid = threadIdx.y*64 + lane;
  __shared__ float sab[2];
  if (tid < 64){
    size_t bse = (((size_t)(iter-1)*3)*NSLOT + tid)*PAD;
    double pap = dots[bse];
    double apap= dots[bse + (size_t)NSLOT*PAD];
    double rr  = dots[bse + (size_t)2*NSLOT*PAD];
    #pragma unroll
    for (int o=32;o>0;o>>=1){ pap+=__shfl_down(pap,o,64); apap+=__shfl_down(apap,o,64); rr+=__shfl_down(rr,o,64); }
    if (tid==0){
      double al = (pap!=0.0)? rr/pap : 0.0;
      double rrn = al*al*apap - rr;
      sab[0]=(float)al;
      sab[1]=(rr!=0.0)? (float)(rrn/rr) : 0.f;
    }
  }
  __syncthreads();
  float alpha=sab[0], beta=sab[1];

  int w = blockIdx.x*4 + threadIdx.y;
  int plane = w >> 6;
  int a = (w & 63) * BAND;
  const h16* rp = rprev + (size_t)plane*SPATIAL;
  h16* rn = rnext + (size_t)plane*SPATIAL;
  const h16* pp = pprev + (size_t)plane*SPATIAL;
  h16* pn = pnext + (size_t)plane*SPATIAL;
  h16* xp = xv + (size_t)plane*SPATIAL;
  const uint32_t* ub = bits + ((size_t)(plane/CH)<<13);
  int x0 = lane*8;
  int wofs = lane>>2;
  int bit0 = (lane&3)*8;

  float wpm_m[10], wpm_c[10], wpm_p[10];
  float wpi_2[10], wpi_1[10], wpi_0[10];
  float t[8];
  loadh(pp, a-2, x0, t); bwin(t, wpm_m, lane);
  loadh(pp, a-1, x0, t); bwin(t, wpm_c, lane);
  #pragma unroll
  for (int j=0;j<10;j++){ wpi_2[j]=0.f; wpi_1[j]=0.f; }
  uint32_t ub_1 = 0;
  double d_pap=0.0, d_apap=0.0, d_rr=0.0;
  for (int y=a-1; y<=a+BAND; ++y){
    loadh(pp, y+1, x0, t); bwin(t, wpm_p, lane);
    float rm1[8]; loadh(rp, y, x0, rm1);
    uint32_t uy = ((unsigned)y<HW)? ub[y*16 + wofs] : 0u;
    float ri[8], pi[8];
    #pragma unroll
    for (int e=0;e<8;e++){
      float unk = (float)((uy>>(bit0+e))&1u);
      float Ap = unk * (swE(y, x0+e)*wpm_c[e+1] - accE(wpm_m,wpm_c,wpm_p,e));
      float rv = rm1[e] - alpha*Ap;
      rv = (float)(h16)rv;                 // match stored precision
      float pv = rv + beta*wpm_c[e+1];
      pv = (float)(h16)pv;
      ri[e]=rv; pi[e]=pv;
    }
    if (y>=a && y<a+BAND){
      h16x8 xc = *(const h16x8*)(xp + y*HW + x0);
      h16x8 xo, rw, pw;
      #pragma unroll
      for (int e=0;e<8;e++){
        xo[e] = (h16)((float)xc[e] + alpha*wpm_c[e+1]);
        rw[e] = (h16)ri[e];
        pw[e] = (h16)pi[e];
        d_rr += (double)ri[e]*(double)ri[e];
      }
      *(h16x8*)(xp + y*HW + x0) = xo;
      if (!last){
        *(h16x8*)(rn + y*HW + x0) = rw;
        *(h16x8*)(pn + y*HW + x0) = pw;
      }
    }
    bwin(pi, wpi_0, lane);
    if (!last && y-1>=a && y-1<a+BAND){
      #pragma unroll
      for (int e=0;e<8;e++){
        float unk = (float)((ub_1>>(bit0+e))&1u);
        float Ap = unk * (swE(y-1, x0+e)*wpi_1[e+1] - accE(wpi_2,wpi_1,wpi_0,e));
        d_pap += (double)wpi_1[e+1]*(double)Ap;
        d_apap+= (double)Ap*(double)Ap;
      }
    }
    #pragma unroll
    for (int j=0;j<10;j++){ wpm_m[j]=wpm_c[j]; wpm_c[j]=wpm_p[j]; wpi_2[j]=wpi_1[j]; wpi_1[j]=wpi_0[j]; }
    ub_1 = uy;
  }
  if (!last) dots_emit(d_pap,d_apap,d_rr,tid,dots,iter);
}

__global__ __launch_bounds__(256) void k_final(const float* __restrict__ img, const float* __restrict__ noise,
    const uint32_t* __restrict__ bits, const h16* __restrict__ xv, float* __restrict__ out){
  int lane = threadIdx.x;
  int y = blockIdx.x*4 + threadIdx.y;
  int bc = blockIdx.y;
  size_t base = (size_t)bc*SPATIAL;
  int x0 = lane*8;
  int sp0 = y*HW + x0;
  const uint32_t* ub = bits + ((size_t)(bc/CH)<<13);
  f32x8 iv = *(const f32x8*)(img+base+sp0);
  f32x8 nv = *(const f32x8*)(noise+base+sp0);
  h16x8 xc = *(const h16x8*)(xv+base+sp0);
  uint32_t wb = ub[y*16 + (lane>>2)];
  int bit0 = (lane&3)*8;
  f32x8 ov;
  #pragma unroll
  for (int e=0;e<8;e++){
    ov[e] = ((wb>>(bit0+e))&1u) ? ((float)xc[e] + 0.01f*nv[e]) : iv[e];
  }
  *(f32x8*)(out+base+sp0) = ov;
}

extern "C" void kernel_launch(void* const* d_in, const int* in_sizes, int n_in,
                              void* d_out, int out_size, void* d_ws, size_t ws_size,
                              hipStream_t stream) {
  const float* img  =(const float*)d_in[0];
  const int*   smap =(const int*)d_in[1];
  const float* noise=(const float*)d_in[2];
  float* out=(float*)d_out;
  float* maskout = out + NELEM;          // mask output region (B,H,W)
  char* ws=(char*)d_ws;
  h16* rA =(h16*)(ws+OFF_RA);
  h16* rB =(h16*)(ws+OFF_RB);
  h16* pA =(h16*)(ws+OFF_PA);
  h16* pB =(h16*)(ws+OFF_PB);
  h16* xv =(h16*)(ws+OFF_X);
  uint32_t* bits=(uint32_t*)(ws+OFF_BITS);
  double* dots=(double*)(ws+OFF_DOTS);
  int* hc=(int*)(ws+OFF_HC);
  int* hf=(int*)(ws+OFF_HF);
  int* sel=(int*)(ws+OFF_SEL);
  int* tiecnt=(int*)(ws+OFF_TC);
  int* tielist=(int*)(ws+OFF_TL);

  // zero x, dots, hists, sel, tiecnt (bits fully overwritten; tielist guarded)
  hipMemsetAsync(ws+OFF_X, 0, OFF_TL-OFF_X, stream);

  // mask pipeline
  k_hist_coarse<<<dim3(64,16),256,0,stream>>>(smap,hc);
  k_select_coarse<<<1,dim3(64,16),0,stream>>>(hc,sel);
  k_hist_fine<<<dim3(64,16),256,0,stream>>>(smap,sel,hf);
  k_select_fine<<<1,dim3(64,16),0,stream>>>(hf,sel);
  k_mask_init<<<SPATIAL*BATCH/256,256,0,stream>>>(smap,sel,maskout,bits,tiecnt,tielist);
  k_tie_fix<<<16,256,0,stream>>>(sel,tiecnt,tielist,maskout,bits);

  // CG: 768 blocks x (64,4); each wave = 8-row band
  dim3 gcg(NPLANE*HW/BAND/4), bcg(64,4);
  k_rhs<<<gcg,bcg,0,stream>>>(img,bits,rA,dots);

  for (int i=1;i<=NITER;i++){
    const h16* rprev = (i&1)? rA : rB;
    h16* rnext       = (i&1)? rB : rA;
    const h16* pprev = (i==1)? rA : ((i&1)? pB : pA);
    h16* pnext       = (i&1)? pA : pB;
    k_cg<<<gcg,bcg,0,stream>>>(rprev,rnext,pprev,pnext,xv,bits,dots,i,(i==NITER)?1:0);
  }

  k_final<<<dim3(HW/4,NPLANE),bcg,0,stream>>>(img,noise,bits,xv,out);
}

// Round 6
// 1511.977 us; speedup vs baseline: 30.0061x; 1.4393x over previous
//
#include <hip/hip_runtime.h>
#include <cstdint>
#include <cstddef>

#define HW 512
#define SPATIAL (HW*HW)              // 262144
#define BATCH 16
#define CH 3
#define NPLANE (BATCH*CH)            // 48
#define NELEM ((size_t)NPLANE*SPATIAL) // 12582912
#define K_SELECT 78643
#define NITER 32
#define CAP_TIES 4096
#define NSLOT 64
#define PAD 8     // doubles per slot -> one 64B line per slot
#define BAND 4    // rows per wave in CG kernels (128 bands/plane)

typedef _Float16 h16;
typedef __attribute__((ext_vector_type(8))) _Float16 h16x8;  // 16B
typedef __attribute__((ext_vector_type(8))) float f32x8;     // 32B

// workspace layout: 3 rotating p buffers, x, bits, dots, betas, hists
static const size_t OFF_P0   = 0;                      // h16[NELEM]
static const size_t OFF_P1   = NELEM*2;                // h16[NELEM]
static const size_t OFF_P2   = NELEM*4;                // h16[NELEM]
static const size_t OFF_BITS = NELEM*6;                // uint32[BATCH*8192] = 512KB (fully written)
static const size_t OFF_X    = OFF_BITS + (size_t)BATCH*8192*4;   // h16[NELEM]  <- memset starts here
static const size_t OFF_DOTS = OFF_X + NELEM*2;        // double[(NITER+1)*3*NSLOT*PAD]
static const size_t OFF_BETA = OFF_DOTS + (size_t)(NITER+1)*3*NSLOT*PAD*8;  // double[NITER+1]
static const size_t OFF_HC   = OFF_BETA + (size_t)(NITER+1)*8;
static const size_t OFF_HF   = OFF_HC + (size_t)BATCH*1024*4;
static const size_t OFF_SEL  = OFF_HF + (size_t)BATCH*1024*4;     // int[16][4]
static const size_t OFF_TC   = OFF_SEL + (size_t)BATCH*4*4;       // int[16]
static const size_t OFF_TL   = OFF_TC + 64;                       // int[16][CAP_TIES]

// ---------------- mask pipeline ----------------
__global__ __launch_bounds__(256) void k_hist_coarse(const int* __restrict__ smap, int* __restrict__ hist){
  __shared__ int h[1024];
  int tid = threadIdx.x;
  for (int j=tid;j<1024;j+=256) h[j]=0;
  __syncthreads();
  int b = blockIdx.y;
  int base = b*SPATIAL + blockIdx.x*4096;
  #pragma unroll
  for (int e=0;e<16;e++){
    int v = smap[base + e*256 + tid];
    atomicAdd(&h[v>>10], 1);
  }
  __syncthreads();
  for (int j=tid;j<1024;j+=256){ int c=h[j]; if(c) atomicAdd(&hist[b*1024+j], c); }
}

// one wave per batch: suffix-scan over 64 lanes x 16 bins
__global__ __launch_bounds__(1024) void k_select_coarse(const int* __restrict__ hist, int* __restrict__ sel){
  int lane = threadIdx.x, b = threadIdx.y;
  const int* h = hist + b*1024;
  int loc[16]; int s=0;
  #pragma unroll
  for (int j=0;j<16;j++){ loc[j]=h[lane*16+j]; s+=loc[j]; }
  int T=s;
  #pragma unroll
  for (int o=1;o<64;o<<=1){ int t=__shfl_down(T,o,64); if (lane+o<64) T+=t; }
  int S = T - s;  // sum over lanes > lane
  if (S < K_SELECT && T >= K_SELECT){
    int acc=S;
    #pragma unroll
    for (int j=15;j>=0;j--){
      acc+=loc[j];
      if (acc>=K_SELECT){ sel[b*4+0]=lane*16+j; sel[b*4+1]=acc-loc[j]; break; }
    }
  }
}

__global__ __launch_bounds__(256) void k_hist_fine(const int* __restrict__ smap, const int* __restrict__ sel, int* __restrict__ hist){
  __shared__ int h[1024];
  int tid=threadIdx.x;
  for (int j=tid;j<1024;j+=256) h[j]=0;
  __syncthreads();
  int b=blockIdx.y;
  int cb = sel[b*4+0];
  int base = b*SPATIAL + blockIdx.x*4096;
  #pragma unroll
  for (int e=0;e<16;e++){
    int v = smap[base+e*256+tid];
    if ((v>>10)==cb) atomicAdd(&h[v&1023],1);
  }
  __syncthreads();
  for (int j=tid;j<1024;j+=256){ int c=h[j]; if(c) atomicAdd(&hist[b*1024+j],c); }
}

__global__ __launch_bounds__(1024) void k_select_fine(const int* __restrict__ hist, int* __restrict__ sel){
  int lane = threadIdx.x, b = threadIdx.y;
  const int* h = hist + b*1024;
  int cb = sel[b*4+0];
  int acc0 = sel[b*4+1];
  int loc[16]; int s=0;
  #pragma unroll
  for (int j=0;j<16;j++){ loc[j]=h[lane*16+j]; s+=loc[j]; }
  int T=s;
  #pragma unroll
  for (int o=1;o<64;o<<=1){ int t=__shfl_down(T,o,64); if (lane+o<64) T+=t; }
  int S = acc0 + (T - s);
  int Ti = acc0 + T;
  if (S < K_SELECT && Ti >= K_SELECT){
    int acc=S;
    #pragma unroll
    for (int j=15;j>=0;j--){
      acc+=loc[j];
      if (acc>=K_SELECT){
        sel[b*4+2]=(cb<<10)|(lane*16+j);
        sel[b*4+3]=K_SELECT-(acc-loc[j]);
        break;
      }
    }
  }
}

// mask + bit-pack (bit=1 means unknown) in one pass
__global__ __launch_bounds__(256) void k_mask_init(const int* __restrict__ smap, const int* __restrict__ sel,
                                                   float* __restrict__ mask, uint32_t* __restrict__ bits,
                                                   int* __restrict__ tiecnt, int* __restrict__ tielist){
  int idx = blockIdx.x*256+threadIdx.x;  // < 4194304
  int b = idx>>18;
  int v = smap[idx];
  int T = sel[b*4+2];
  bool unk = (v>T);
  unsigned long long bal = __ballot(unk);
  if ((threadIdx.x&63)==0){
    bits[idx>>5]     = (uint32_t)(bal);
    bits[(idx>>5)+1] = (uint32_t)(bal>>32);
  }
  if (v==T){
    int t = atomicAdd(&tiecnt[b],1);
    if (t<CAP_TIES) tielist[b*CAP_TIES+t] = idx & (SPATIAL-1);
  }
  mask[idx]= unk? 0.f : 1.f;
}

__global__ __launch_bounds__(256) void k_tie_fix(const int* __restrict__ sel, const int* __restrict__ tiecnt,
                                                 const int* __restrict__ tielist, float* __restrict__ mask,
                                                 uint32_t* __restrict__ bits){
  int b=blockIdx.x;
  int n = tiecnt[b]; if (n>CAP_TIES) n=CAP_TIES;
  int need = sel[b*4+3];
  for (int e=threadIdx.x; e<n; e+=256){
    int me = tielist[b*CAP_TIES+e];
    int rank=0;
    for (int j=0;j<n;j++) rank += (tielist[b*CAP_TIES+j] < me) ? 1:0;
    if (rank<need){
      mask[b*SPATIAL+me]=0.f;
      atomicOr(&bits[(b<<13)+(me>>5)], 1u<<(me&31));
    }
  }
}

// ---------------- stencil helpers ----------------
__device__ __forceinline__ void bwin(const float v[8], float w[10], int lane){
  float up = __shfl_up(v[7],1,64);
  float dn = __shfl_down(v[0],1,64);
  w[0] = (lane==0)?0.f:up;
  #pragma unroll
  for(int e=0;e<8;e++) w[e+1]=v[e];
  w[9] = (lane==63)?0.f:dn;
}
__device__ __forceinline__ float accE(const float* wm, const float* wc, const float* wp, int e){
  const float WE=1.f/6.f, WC=1.f/12.f;
  return WE*(wm[e+1]+wp[e+1]+wc[e]+wc[e+2]) + WC*(wm[e]+wm[e+2]+wp[e]+wp[e+2]);
}
__device__ __forceinline__ float swE(int y,int xg){
  const float WE=1.f/6.f, WC=1.f/12.f;
  float fym=(y>0)?1.f:0.f, fyp=(y<HW-1)?1.f:0.f;
  float xmf=(xg>0)?1.f:0.f, xpf=(xg<HW-1)?1.f:0.f;
  return WE*(fym+fyp+xmf+xpf) + WC*(fym*xmf+fym*xpf+fyp*xmf+fyp*xpf);
}
__device__ __forceinline__ void loadh(const h16* buf, int y, int x0, float v[8]){
  if ((unsigned)y < HW){
    h16x8 t = *(const h16x8*)(buf + y*HW + x0);
    #pragma unroll
    for (int e=0;e<8;e++) v[e]=(float)t[e];
  } else {
    #pragma unroll
    for (int e=0;e<8;e++) v[e]=0.f;
  }
}

// 3-dot block reduce + atomic emit into slot arrays
__device__ __forceinline__ void dots_emit(double a,double b,double c,int tid,double* dst,int it){
  #pragma unroll
  for (int o=32;o>0;o>>=1){ a+=__shfl_down(a,o,64); b+=__shfl_down(b,o,64); c+=__shfl_down(c,o,64); }
  __shared__ double s3[3][4];
  int wv = tid>>6;
  if ((tid&63)==0){ s3[0][wv]=a; s3[1][wv]=b; s3[2][wv]=c; }
  __syncthreads();
  if (tid==0){
    double A=s3[0][0]+s3[0][1]+s3[0][2]+s3[0][3];
    double B=s3[1][0]+s3[1][1]+s3[1][2]+s3[1][3];
    double C=s3[2][0]+s3[2][1]+s3[2][2]+s3[2][3];
    int slot = blockIdx.x & (NSLOT-1);
    atomicAdd(&dst[(((size_t)it*3+0)*NSLOT+slot)*PAD], A);
    atomicAdd(&dst[(((size_t)it*3+1)*NSLOT+slot)*PAD], B);
    atomicAdd(&dst[(((size_t)it*3+2)*NSLOT+slot)*PAD], C);
  }
}

// ---------------- rhs: p0 (= r0) = unk*stencil(known*img); dots pAp0, ApAp0, rr0 ----------------
__global__ __launch_bounds__(256) void k_rhs(const float* __restrict__ img, const uint32_t* __restrict__ bits,
                                             h16* __restrict__ p0, double* __restrict__ dots){
  int lane=threadIdx.x; int tid=threadIdx.y*64+lane;
  int w = blockIdx.x*4+threadIdx.y;
  int plane = w>>7; int a = (w&127)*BAND;
  const float* ip = img + (size_t)plane*SPATIAL;
  h16* rn = p0 + (size_t)plane*SPATIAL;
  const uint32_t* ub = bits + ((size_t)(plane/CH)<<13);
  int x0=lane*8, wofs=lane>>2, bit0=(lane&3)*8;
  float wv_m[10], wv_c[10], wv_p[10], wr_2[10], wr_1[10], wr_0[10];
  float t[8];
  auto loadv=[&](int y, float v[8]){
    if ((unsigned)y < HW){
      f32x8 iv = *(const f32x8*)(ip + y*HW + x0);
      uint32_t uy = ub[y*16 + wofs];
      #pragma unroll
      for (int e=0;e<8;e++) v[e] = ((uy>>(bit0+e))&1u)? 0.f : iv[e];
    } else {
      #pragma unroll
      for (int e=0;e<8;e++) v[e]=0.f;
    }
  };
  loadv(a-2,t); bwin(t,wv_m,lane);
  loadv(a-1,t); bwin(t,wv_c,lane);
  #pragma unroll
  for (int j=0;j<10;j++){ wr_2[j]=0.f; wr_1[j]=0.f; }
  uint32_t ub_1=0;
  double d_pap=0.0, d_apap=0.0, d_rr=0.0;
  for (int y=a-1; y<=a+BAND; ++y){
    loadv(y+1,t); bwin(t,wv_p,lane);
    uint32_t uy = ((unsigned)y<HW)? ub[y*16+wofs] : 0u;
    float rr8[8];
    #pragma unroll
    for (int e=0;e<8;e++){
      float rv = ((uy>>(bit0+e))&1u)? accE(wv_m,wv_c,wv_p,e) : 0.f;
      rr8[e] = (float)(h16)rv;
    }
    if (y>=a && y<a+BAND){
      h16x8 rw;
      #pragma unroll
      for (int e=0;e<8;e++){ rw[e]=(h16)rr8[e]; d_rr += (double)rr8[e]*(double)rr8[e]; }
      *(h16x8*)(rn + y*HW + x0) = rw;
    }
    bwin(rr8, wr_0, lane);
    if (y>=a+1){
      #pragma unroll
      for (int e=0;e<8;e++){
        float unk = (float)((ub_1>>(bit0+e))&1u);
        float Ap = unk * (swE(y-1,x0+e)*wr_1[e+1] - accE(wr_2,wr_1,wr_0,e));
        d_pap += (double)wr_1[e+1]*(double)Ap;
        d_apap+= (double)Ap*(double)Ap;
      }
    }
    #pragma unroll
    for (int j=0;j<10;j++){ wv_m[j]=wv_c[j]; wv_c[j]=wv_p[j]; wr_2[j]=wr_1[j]; wr_1[j]=wr_0[j]; }
    ub_1 = uy;
  }
  dots_emit(d_pap,d_apap,d_rr,tid,dots,0);
}

// ---------------- merged CG iteration, r-free ----------------
// K(i): alpha=rr_{i-1}/pAp_{i-1}; beta_i=(a^2*ApAp-rr)/rr; r~_{i-1}=p_{i-1}-beta_{i-1}p_{i-2}
//   x += a*p_{i-1};  r_i = r~ - a*Ap_{i-1};  p_i = r_i + beta_i*p_{i-1}
//   dots: pAp_i, ApAp_i, rr_i(direct)
__global__ __launch_bounds__(256) void k_cg(const h16* __restrict__ pm1, const h16* __restrict__ pm2,
    h16* __restrict__ pn, h16* __restrict__ xv, const uint32_t* __restrict__ bits,
    double* __restrict__ dots, double* __restrict__ betas, int iter, int last){
  int lane = threadIdx.x;
  int tid = threadIdx.y*64 + lane;
  __shared__ float sab[3];
  if (tid < 64){
    size_t bse = (((size_t)(iter-1)*3)*NSLOT + tid)*PAD;
    double pap = dots[bse];
    double apap= dots[bse + (size_t)NSLOT*PAD];
    double rr  = dots[bse + (size_t)2*NSLOT*PAD];
    #pragma unroll
    for (int o=32;o>0;o>>=1){ pap+=__shfl_down(pap,o,64); apap+=__shfl_down(apap,o,64); rr+=__shfl_down(rr,o,64); }
    if (tid==0){
      double al = (pap!=0.0)? rr/pap : 0.0;
      double rrn = al*al*apap - rr;
      double bi = (rr!=0.0)? rrn/rr : 0.0;
      double bp = (iter>=2)? betas[iter-1] : 0.0;
      sab[0]=(float)al; sab[1]=(float)bp; sab[2]=(float)bi;
      if (blockIdx.x==0) betas[iter]=bi;
    }
  }
  __syncthreads();
  float alpha=sab[0], bprev=sab[1], bnext=sab[2];

  int w = blockIdx.x*4 + threadIdx.y;
  int plane = w >> 7;
  int a = (w & 127) * BAND;
  const h16* P1 = pm1 + (size_t)plane*SPATIAL;
  const h16* P2 = pm2 + (size_t)plane*SPATIAL;
  h16* PN = pn + (size_t)plane*SPATIAL;
  h16* XP = xv + (size_t)plane*SPATIAL;
  const uint32_t* ub = bits + ((size_t)(plane/CH)<<13);
  int x0 = lane*8;
  int wofs = lane>>2;
  int bit0 = (lane&3)*8;

  float w1m[10], w1c[10], w1p[10];   // p_{i-1} windows
  float wi2[10], wi1[10], wi0[10];   // p_i windows
  float t[8];
  loadh(P1, a-2, x0, t); bwin(t, w1m, lane);
  loadh(P1, a-1, x0, t); bwin(t, w1c, lane);
  #pragma unroll
  for (int j=0;j<10;j++){ wi2[j]=0.f; wi1[j]=0.f; }
  uint32_t ub_1 = 0;
  double d_pap=0.0, d_apap=0.0, d_rr=0.0;
  for (int y=a-1; y<=a+BAND; ++y){
    loadh(P1, y+1, x0, t); bwin(t, w1p, lane);
    float r2[8]; loadh(P2, y, x0, r2);
    uint32_t uy = ((unsigned)y<HW)? ub[y*16 + wofs] : 0u;
    float rv8[8], pi[8];
    #pragma unroll
    for (int e=0;e<8;e++){
      float unk = (float)((uy>>(bit0+e))&1u);
      float Ap = unk * (swE(y, x0+e)*w1c[e+1] - accE(w1m,w1c,w1p,e));
      float rt = w1c[e+1] - bprev*r2[e];     // reconstructed r_{i-1}
      float rv = rt - alpha*Ap;
      rv = (float)(h16)rv;
      float pv = rv + bnext*w1c[e+1];
      pv = (float)(h16)pv;
      rv8[e]=rv; pi[e]=pv;
    }
    if (y>=a && y<a+BAND){
      h16x8 xc = *(const h16x8*)(XP + y*HW + x0);
      h16x8 xo, pw;
      #pragma unroll
      for (int e=0;e<8;e++){
        xo[e] = (h16)((float)xc[e] + alpha*w1c[e+1]);
        pw[e] = (h16)pi[e];
        d_rr += (double)rv8[e]*(double)rv8[e];
      }
      *(h16x8*)(XP + y*HW + x0) = xo;
      if (!last) *(h16x8*)(PN + y*HW + x0) = pw;
    }
    bwin(pi, wi0, lane);
    if (!last && y>=a+1){
      #pragma unroll
      for (int e=0;e<8;e++){
        float unk = (float)((ub_1>>(bit0+e))&1u);
        float Ap = unk * (swE(y-1, x0+e)*wi1[e+1] - accE(wi2,wi1,wi0,e));
        d_pap += (double)wi1[e+1]*(double)Ap;
        d_apap+= (double)Ap*(double)Ap;
      }
    }
    #pragma unroll
    for (int j=0;j<10;j++){ w1m[j]=w1c[j]; w1c[j]=w1p[j]; wi2[j]=wi1[j]; wi1[j]=wi0[j]; }
    ub_1 = uy;
  }
  if (!last) dots_emit(d_pap,d_apap,d_rr,tid,dots,iter);
}

__global__ __launch_bounds__(256) void k_final(const float* __restrict__ img, const float* __restrict__ noise,
    const uint32_t* __restrict__ bits, const h16* __restrict__ xv, float* __restrict__ out){
  int lane = threadIdx.x;
  int y = blockIdx.x*4 + threadIdx.y;
  int bc = blockIdx.y;
  size_t base = (size_t)bc*SPATIAL;
  int x0 = lane*8;
  int sp0 = y*HW + x0;
  const uint32_t* ub = bits + ((size_t)(bc/CH)<<13);
  f32x8 iv = *(const f32x8*)(img+base+sp0);
  f32x8 nv = *(const f32x8*)(noise+base+sp0);
  h16x8 xc = *(const h16x8*)(xv+base+sp0);
  uint32_t wb = ub[y*16 + (lane>>2)];
  int bit0 = (lane&3)*8;
  f32x8 ov;
  #pragma unroll
  for (int e=0;e<8;e++){
    ov[e] = ((wb>>(bit0+e))&1u) ? ((float)xc[e] + 0.01f*nv[e]) : iv[e];
  }
  *(f32x8*)(out+base+sp0) = ov;
}

extern "C" void kernel_launch(void* const* d_in, const int* in_sizes, int n_in,
                              void* d_out, int out_size, void* d_ws, size_t ws_size,
                              hipStream_t stream) {
  const float* img  =(const float*)d_in[0];
  const int*   smap =(const int*)d_in[1];
  const float* noise=(const float*)d_in[2];
  float* out=(float*)d_out;
  float* maskout = out + NELEM;          // mask output region (B,H,W)
  char* ws=(char*)d_ws;
  h16* pbuf[3] = { (h16*)(ws+OFF_P0), (h16*)(ws+OFF_P1), (h16*)(ws+OFF_P2) };
  h16* xv =(h16*)(ws+OFF_X);
  uint32_t* bits=(uint32_t*)(ws+OFF_BITS);
  double* dots=(double*)(ws+OFF_DOTS);
  double* betas=(double*)(ws+OFF_BETA);
  int* hc=(int*)(ws+OFF_HC);
  int* hf=(int*)(ws+OFF_HF);
  int* sel=(int*)(ws+OFF_SEL);
  int* tiecnt=(int*)(ws+OFF_TC);
  int* tielist=(int*)(ws+OFF_TL);

  // zero x, dots, betas, hists, sel, tiecnt (bits fully overwritten; tielist guarded)
  hipMemsetAsync(ws+OFF_X, 0, OFF_TL-OFF_X, stream);

  // mask pipeline
  k_hist_coarse<<<dim3(64,16),256,0,stream>>>(smap,hc);
  k_select_coarse<<<1,dim3(64,16),0,stream>>>(hc,sel);
  k_hist_fine<<<dim3(64,16),256,0,stream>>>(smap,sel,hf);
  k_select_fine<<<1,dim3(64,16),0,stream>>>(hf,sel);
  k_mask_init<<<SPATIAL*BATCH/256,256,0,stream>>>(smap,sel,maskout,bits,tiecnt,tielist);
  k_tie_fix<<<16,256,0,stream>>>(sel,tiecnt,tielist,maskout,bits);

  // CG: 1536 blocks x (64,4); each wave = 4-row band
  dim3 gcg(NPLANE*(HW/BAND)/4), bcg(64,4);
  k_rhs<<<gcg,bcg,0,stream>>>(img,bits,pbuf[0],dots);

  for (int i=1;i<=NITER;i++){
    const h16* pm1 = pbuf[(i-1)%3];
    const h16* pm2 = (i>=2)? pbuf[(i-2)%3] : pbuf[0];   // i==1: bprev=0, pm2 values unused but must be finite
    h16* pn        = pbuf[i%3];
    k_cg<<<gcg,bcg,0,stream>>>(pm1,pm2,pn,xv,bits,dots,betas,i,(i==NITER)?1:0);
  }

  k_final<<<dim3(HW/4,NPLANE),bcg,0,stream>>>(img,noise,bits,xv,out);
}

// Round 7
// 927.813 us; speedup vs baseline: 48.8984x; 1.6296x over previous
//
#include <hip/hip_runtime.h>
#include <cstdint>
#include <cstddef>

#define HW 512
#define SPATIAL (HW*HW)              // 262144
#define BATCH 16
#define CH 3
#define NPLANE (BATCH*CH)            // 48
#define NELEM ((size_t)NPLANE*SPATIAL) // 12582912
#define K_SELECT 78643
#define NITER 24
#define CAP_TIES 4096
#define NSLOT 64
#define PAD 8     // doubles per slot -> one 64B line per slot
#define BAND 4    // rows per wave in CG kernels (128 bands/plane)

typedef _Float16 h16;
typedef __attribute__((ext_vector_type(8))) _Float16 h16x8;  // 16B
typedef __attribute__((ext_vector_type(8))) float f32x8;     // 32B

// workspace layout: 3 rotating p buffers, x, bits, dots, betas/alphas, hists
static const size_t OFF_P0   = 0;                      // h16[NELEM]
static const size_t OFF_P1   = NELEM*2;                // h16[NELEM]
static const size_t OFF_P2   = NELEM*4;                // h16[NELEM]
static const size_t OFF_BITS = NELEM*6;                // uint32[BATCH*8192] = 512KB (fully written)
static const size_t OFF_X    = OFF_BITS + (size_t)BATCH*8192*4;   // h16[NELEM]  <- memset starts here
static const size_t OFF_DOTS = OFF_X + NELEM*2;        // double[(NITER+1)*3*NSLOT*PAD]
static const size_t OFF_BETA = OFF_DOTS + (size_t)(NITER+1)*3*NSLOT*PAD*8;  // double[NITER+1]
static const size_t OFF_ALPH = OFF_BETA + (size_t)(NITER+1)*8;              // double[NITER+1]
static const size_t OFF_HC   = OFF_ALPH + (size_t)(NITER+1)*8;
static const size_t OFF_HF   = OFF_HC + (size_t)BATCH*1024*4;
static const size_t OFF_SEL  = OFF_HF + (size_t)BATCH*1024*4;     // int[16][4]
static const size_t OFF_TC   = OFF_SEL + (size_t)BATCH*4*4;       // int[16]
static const size_t OFF_TL   = OFF_TC + 64;                       // int[16][CAP_TIES]

// ---------------- mask pipeline ----------------
__global__ __launch_bounds__(256) void k_hist_coarse(const int* __restrict__ smap, int* __restrict__ hist){
  __shared__ int h[1024];
  int tid = threadIdx.x;
  for (int j=tid;j<1024;j+=256) h[j]=0;
  __syncthreads();
  int b = blockIdx.y;
  int base = b*SPATIAL + blockIdx.x*4096;
  #pragma unroll
  for (int e=0;e<16;e++){
    int v = smap[base + e*256 + tid];
    atomicAdd(&h[v>>10], 1);
  }
  __syncthreads();
  for (int j=tid;j<1024;j+=256){ int c=h[j]; if(c) atomicAdd(&hist[b*1024+j], c); }
}

// one wave per batch: suffix-scan over 64 lanes x 16 bins
__global__ __launch_bounds__(1024) void k_select_coarse(const int* __restrict__ hist, int* __restrict__ sel){
  int lane = threadIdx.x, b = threadIdx.y;
  const int* h = hist + b*1024;
  int loc[16]; int s=0;
  #pragma unroll
  for (int j=0;j<16;j++){ loc[j]=h[lane*16+j]; s+=loc[j]; }
  int T=s;
  #pragma unroll
  for (int o=1;o<64;o<<=1){ int t=__shfl_down(T,o,64); if (lane+o<64) T+=t; }
  int S = T - s;  // sum over lanes > lane
  if (S < K_SELECT && T >= K_SELECT){
    int acc=S;
    #pragma unroll
    for (int j=15;j>=0;j--){
      acc+=loc[j];
      if (acc>=K_SELECT){ sel[b*4+0]=lane*16+j; sel[b*4+1]=acc-loc[j]; break; }
    }
  }
}

__global__ __launch_bounds__(256) void k_hist_fine(const int* __restrict__ smap, const int* __restrict__ sel, int* __restrict__ hist){
  __shared__ int h[1024];
  int tid=threadIdx.x;
  for (int j=tid;j<1024;j+=256) h[j]=0;
  __syncthreads();
  int b=blockIdx.y;
  int cb = sel[b*4+0];
  int base = b*SPATIAL + blockIdx.x*4096;
  #pragma unroll
  for (int e=0;e<16;e++){
    int v = smap[base+e*256+tid];
    if ((v>>10)==cb) atomicAdd(&h[v&1023],1);
  }
  __syncthreads();
  for (int j=tid;j<1024;j+=256){ int c=h[j]; if(c) atomicAdd(&hist[b*1024+j],c); }
}

__global__ __launch_bounds__(1024) void k_select_fine(const int* __restrict__ hist, int* __restrict__ sel){
  int lane = threadIdx.x, b = threadIdx.y;
  const int* h = hist + b*1024;
  int cb = sel[b*4+0];
  int acc0 = sel[b*4+1];
  int loc[16]; int s=0;
  #pragma unroll
  for (int j=0;j<16;j++){ loc[j]=h[lane*16+j]; s+=loc[j]; }
  int T=s;
  #pragma unroll
  for (int o=1;o<64;o<<=1){ int t=__shfl_down(T,o,64); if (lane+o<64) T+=t; }
  int S = acc0 + (T - s);
  int Ti = acc0 + T;
  if (S < K_SELECT && Ti >= K_SELECT){
    int acc=S;
    #pragma unroll
    for (int j=15;j>=0;j--){
      acc+=loc[j];
      if (acc>=K_SELECT){
        sel[b*4+2]=(cb<<10)|(lane*16+j);
        sel[b*4+3]=K_SELECT-(acc-loc[j]);
        break;
      }
    }
  }
}

// mask + bit-pack (bit=1 means unknown) in one pass
__global__ __launch_bounds__(256) void k_mask_init(const int* __restrict__ smap, const int* __restrict__ sel,
                                                   float* __restrict__ mask, uint32_t* __restrict__ bits,
                                                   int* __restrict__ tiecnt, int* __restrict__ tielist){
  int idx = blockIdx.x*256+threadIdx.x;  // < 4194304
  int b = idx>>18;
  int v = smap[idx];
  int T = sel[b*4+2];
  bool unk = (v>T);
  unsigned long long bal = __ballot(unk);
  if ((threadIdx.x&63)==0){
    bits[idx>>5]     = (uint32_t)(bal);
    bits[(idx>>5)+1] = (uint32_t)(bal>>32);
  }
  if (v==T){
    int t = atomicAdd(&tiecnt[b],1);
    if (t<CAP_TIES) tielist[b*CAP_TIES+t] = idx & (SPATIAL-1);
  }
  mask[idx]= unk? 0.f : 1.f;
}

__global__ __launch_bounds__(256) void k_tie_fix(const int* __restrict__ sel, const int* __restrict__ tiecnt,
                                                 const int* __restrict__ tielist, float* __restrict__ mask,
                                                 uint32_t* __restrict__ bits){
  int b=blockIdx.x;
  int n = tiecnt[b]; if (n>CAP_TIES) n=CAP_TIES;
  int need = sel[b*4+3];
  for (int e=threadIdx.x; e<n; e+=256){
    int me = tielist[b*CAP_TIES+e];
    int rank=0;
    for (int j=0;j<n;j++) rank += (tielist[b*CAP_TIES+j] < me) ? 1:0;
    if (rank<need){
      mask[b*SPATIAL+me]=0.f;
      atomicOr(&bits[(b<<13)+(me>>5)], 1u<<(me&31));
    }
  }
}

// ---------------- stencil helpers ----------------
__device__ __forceinline__ void bwin(const float v[8], float w[10], int lane){
  float up = __shfl_up(v[7],1,64);
  float dn = __shfl_down(v[0],1,64);
  w[0] = (lane==0)?0.f:up;
  #pragma unroll
  for(int e=0;e<8;e++) w[e+1]=v[e];
  w[9] = (lane==63)?0.f:dn;
}
__device__ __forceinline__ float accE(const float* wm, const float* wc, const float* wp, int e){
  const float WE=1.f/6.f, WC=1.f/12.f;
  return WE*(wm[e+1]+wp[e+1]+wc[e]+wc[e+2]) + WC*(wm[e]+wm[e+2]+wp[e]+wp[e+2]);
}
__device__ __forceinline__ void loadh(const h16* buf, int y, int x0, float v[8]){
  if ((unsigned)y < HW){
    h16x8 t = *(const h16x8*)(buf + y*HW + x0);
    #pragma unroll
    for (int e=0;e<8;e++) v[e]=(float)t[e];
  } else {
    #pragma unroll
    for (int e=0;e<8;e++) v[e]=0.f;
  }
}

// 3-dot (f32 in-wave) block reduce + f64 atomic emit
__device__ __forceinline__ void dots_emit(float a,float b,float c,int tid,double* dst,int it){
  #pragma unroll
  for (int o=32;o>0;o>>=1){ a+=__shfl_down(a,o,64); b+=__shfl_down(b,o,64); c+=__shfl_down(c,o,64); }
  __shared__ double s3[3][4];
  int wv = tid>>6;
  if ((tid&63)==0){ s3[0][wv]=(double)a; s3[1][wv]=(double)b; s3[2][wv]=(double)c; }
  __syncthreads();
  if (tid==0){
    double A=s3[0][0]+s3[0][1]+s3[0][2]+s3[0][3];
    double B=s3[1][0]+s3[1][1]+s3[1][2]+s3[1][3];
    double C=s3[2][0]+s3[2][1]+s3[2][2]+s3[2][3];
    int slot = blockIdx.x & (NSLOT-1);
    atomicAdd(&dst[(((size_t)it*3+0)*NSLOT+slot)*PAD], A);
    atomicAdd(&dst[(((size_t)it*3+1)*NSLOT+slot)*PAD], B);
    atomicAdd(&dst[(((size_t)it*3+2)*NSLOT+slot)*PAD], C);
  }
}

// sw = WE*(u+v) + WC*u*v with u = fym+fyp (row-uniform), v = xmf+xpf (lane-const)
#define SW_ROW(u) float t1_=(1.f/6.f)*(u), t2_=(1.f/6.f)+(1.f/12.f)*(u)
#define SW_E(e)   fmaf(t2_, vxe[e], t1_)

// ---------------- rhs: p0 (= r0) = unk*stencil(known*img); dots pAp0, ApAp0, rr0 ----------------
__global__ __launch_bounds__(256) void k_rhs(const float* __restrict__ img, const uint32_t* __restrict__ bits,
                                             h16* __restrict__ p0, double* __restrict__ dots){
  int lane=threadIdx.x; int tid=threadIdx.y*64+lane;
  int w = blockIdx.x*4+threadIdx.y;
  int plane = w>>7; int a = (w&127)*BAND;
  const float* ip = img + (size_t)plane*SPATIAL;
  h16* rn = p0 + (size_t)plane*SPATIAL;
  const uint32_t* ub = bits + ((size_t)(plane/CH)<<13);
  int x0=lane*8, wofs=lane>>2, bit0=(lane&3)*8;
  float vxe[8];
  #pragma unroll
  for (int e=0;e<8;e++){
    int xg=x0+e;
    vxe[e] = ((xg>0)?1.f:0.f) + ((xg<HW-1)?1.f:0.f);
  }
  float wv_m[10], wv_c[10], wv_p[10], wr_2[10], wr_1[10], wr_0[10];
  float t[8];
  auto loadv=[&](int y, float v[8]){
    if ((unsigned)y < HW){
      f32x8 iv = *(const f32x8*)(ip + y*HW + x0);
      uint32_t uy = ub[y*16 + wofs];
      #pragma unroll
      for (int e=0;e<8;e++) v[e] = ((uy>>(bit0+e))&1u)? 0.f : iv[e];
    } else {
      #pragma unroll
      for (int e=0;e<8;e++) v[e]=0.f;
    }
  };
  loadv(a-2,t); bwin(t,wv_m,lane);
  loadv(a-1,t); bwin(t,wv_c,lane);
  #pragma unroll
  for (int j=0;j<10;j++){ wr_2[j]=0.f; wr_1[j]=0.f; }
  uint32_t ub_1=0;
  float d_pap=0.f, d_apap=0.f, d_rr=0.f;
  #pragma unroll
  for (int j=0;j<BAND+2;j++){
    int y = a-1+j;
    loadv(y+1,t); bwin(t,wv_p,lane);
    uint32_t uy = ((unsigned)y<HW)? ub[y*16+wofs] : 0u;
    float rr8[8];
    #pragma unroll
    for (int e=0;e<8;e++){
      float rv = ((uy>>(bit0+e))&1u)? accE(wv_m,wv_c,wv_p,e) : 0.f;
      rr8[e] = (float)(h16)rv;
    }
    if (j>=1 && j<1+BAND){
      h16x8 rw;
      #pragma unroll
      for (int e=0;e<8;e++){ rw[e]=(h16)rr8[e]; d_rr = fmaf(rr8[e],rr8[e],d_rr); }
      *(h16x8*)(rn + y*HW + x0) = rw;
    }
    bwin(rr8, wr_0, lane);
    if (j>=2){
      int yc = y-1;
      float u = ((yc>0)?1.f:0.f) + ((yc<HW-1)?1.f:0.f);
      SW_ROW(u);
      #pragma unroll
      for (int e=0;e<8;e++){
        float unk = (float)((ub_1>>(bit0+e))&1u);
        float Ap = unk * (SW_E(e)*wr_1[e+1] - accE(wr_2,wr_1,wr_0,e));
        d_pap = fmaf(wr_1[e+1],Ap,d_pap);
        d_apap= fmaf(Ap,Ap,d_apap);
      }
    }
    #pragma unroll
    for (int jj=0;jj<10;jj++){ wv_m[jj]=wv_c[jj]; wv_c[jj]=wv_p[jj]; wr_2[jj]=wr_1[jj]; wr_1[jj]=wr_0[jj]; }
    ub_1 = uy;
  }
  dots_emit(d_pap,d_apap,d_rr,tid,dots,0);
}

// ---------------- merged CG iteration, r-free, deferred-x ----------------
// K(i): a_i=rr_{i-1}/pAp_{i-1}; b_i=(a^2*ApAp-rr)/rr; r~=p_{i-1}-b_{i-1}p_{i-2}
//   r_i = r~ - a_i*Ap_{i-1};  p_i = r_i + b_i*p_{i-1}
//   even i (or last): x += a_i*p_{i-1} + a_{i-1}*p_{i-2}
//   dots: pAp_i, ApAp_i, rr_i(direct, f32 in-wave)
__global__ __launch_bounds__(256) void k_cg(const h16* __restrict__ pm1, const h16* __restrict__ pm2,
    h16* __restrict__ pn, h16* __restrict__ xv, const uint32_t* __restrict__ bits,
    double* __restrict__ dots, double* __restrict__ betas, double* __restrict__ alphas, int iter, int last){
  int lane = threadIdx.x;
  int tid = threadIdx.y*64 + lane;
  __shared__ float sab[4];
  if (tid < 64){
    size_t bse = (((size_t)(iter-1)*3)*NSLOT + tid)*PAD;
    double pap = dots[bse];
    double apap= dots[bse + (size_t)NSLOT*PAD];
    double rr  = dots[bse + (size_t)2*NSLOT*PAD];
    #pragma unroll
    for (int o=32;o>0;o>>=1){ pap+=__shfl_down(pap,o,64); apap+=__shfl_down(apap,o,64); rr+=__shfl_down(rr,o,64); }
    if (tid==0){
      double al = (pap!=0.0)? rr/pap : 0.0;
      double rrn = al*al*apap - rr;
      double bi = (rr!=0.0)? rrn/rr : 0.0;
      double bp = (iter>=2)? betas[iter-1] : 0.0;
      double ap_= (iter>=2)? alphas[iter-1] : 0.0;
      sab[0]=(float)al; sab[1]=(float)bp; sab[2]=(float)bi; sab[3]=(float)ap_;
      if (blockIdx.x==0){ betas[iter]=bi; alphas[iter]=al; }
    }
  }
  __syncthreads();
  float alpha=sab[0], bprev=sab[1], bnext=sab[2], aprev=sab[3];
  int do_x = ((iter&1)==0) || last;

  int w = blockIdx.x*4 + threadIdx.y;
  int plane = w >> 7;
  int a = (w & 127) * BAND;
  const h16* P1 = pm1 + (size_t)plane*SPATIAL;
  const h16* P2 = pm2 + (size_t)plane*SPATIAL;
  h16* PN = pn + (size_t)plane*SPATIAL;
  h16* XP = xv + (size_t)plane*SPATIAL;
  const uint32_t* ub = bits + ((size_t)(plane/CH)<<13);
  int x0 = lane*8;
  int wofs = lane>>2;
  int bit0 = (lane&3)*8;
  float vxe[8];
  #pragma unroll
  for (int e=0;e<8;e++){
    int xg=x0+e;
    vxe[e] = ((xg>0)?1.f:0.f) + ((xg<HW-1)?1.f:0.f);
  }

  float w1m[10], w1c[10], w1p[10];   // p_{i-1} windows
  float wi2[10], wi1[10], wi0[10];   // p_i windows
  float t[8];
  loadh(P1, a-2, x0, t); bwin(t, w1m, lane);
  loadh(P1, a-1, x0, t); bwin(t, w1c, lane);
  #pragma unroll
  for (int j=0;j<10;j++){ wi2[j]=0.f; wi1[j]=0.f; }
  uint32_t ub_1 = 0;
  float d_pap=0.f, d_apap=0.f, d_rr=0.f;
  #pragma unroll
  for (int j=0;j<BAND+2;j++){
    int y = a-1+j;
    loadh(P1, y+1, x0, t); bwin(t, w1p, lane);
    float r2[8]; loadh(P2, y, x0, r2);
    uint32_t uy = ((unsigned)y<HW)? ub[y*16 + wofs] : 0u;
    float u = ((y>0)?1.f:0.f) + ((y<HW-1)?1.f:0.f);
    SW_ROW(u);
    float rv8[8], pi[8];
    #pragma unroll
    for (int e=0;e<8;e++){
      float unk = (float)((uy>>(bit0+e))&1u);
      float Ap = unk * (SW_E(e)*w1c[e+1] - accE(w1m,w1c,w1p,e));
      float rt = w1c[e+1] - bprev*r2[e];     // reconstructed r_{i-1}
      float rv = rt - alpha*Ap;
      rv = (float)(h16)rv;
      float pv = rv + bnext*w1c[e+1];
      pv = (float)(h16)pv;
      rv8[e]=rv; pi[e]=pv;
    }
    if (j>=1 && j<1+BAND){
      h16x8 pw;
      #pragma unroll
      for (int e=0;e<8;e++){
        pw[e] = (h16)pi[e];
        d_rr = fmaf(rv8[e],rv8[e],d_rr);
      }
      if (do_x){
        h16x8 xc = *(const h16x8*)(XP + y*HW + x0);
        h16x8 xo;
        #pragma unroll
        for (int e=0;e<8;e++)
          xo[e] = (h16)((float)xc[e] + alpha*w1c[e+1] + aprev*r2[e]);
        *(h16x8*)(XP + y*HW + x0) = xo;
      }
      if (!last) *(h16x8*)(PN + y*HW + x0) = pw;
    }
    bwin(pi, wi0, lane);
    if (!last && j>=2){
      int yc = y-1;
      float u2 = ((yc>0)?1.f:0.f) + ((yc<HW-1)?1.f:0.f);
      float t1_=(1.f/6.f)*u2, t2_=(1.f/6.f)+(1.f/12.f)*u2;
      #pragma unroll
      for (int e=0;e<8;e++){
        float unk = (float)((ub_1>>(bit0+e))&1u);
        float Ap = unk * (fmaf(t2_,vxe[e],t1_)*wi1[e+1] - accE(wi2,wi1,wi0,e));
        d_pap = fmaf(wi1[e+1],Ap,d_pap);
        d_apap= fmaf(Ap,Ap,d_apap);
      }
    }
    #pragma unroll
    for (int jj=0;jj<10;jj++){ w1m[jj]=w1c[jj]; w1c[jj]=w1p[jj]; wi2[jj]=wi1[jj]; wi1[jj]=wi0[jj]; }
    ub_1 = uy;
  }
  if (!last) dots_emit(d_pap,d_apap,d_rr,tid,dots,iter);
}

__global__ __launch_bounds__(256) void k_final(const float* __restrict__ img, const float* __restrict__ noise,
    const uint32_t* __restrict__ bits, const h16* __restrict__ xv, float* __restrict__ out){
  int lane = threadIdx.x;
  int y = blockIdx.x*4 + threadIdx.y;
  int bc = blockIdx.y;
  size_t base = (size_t)bc*SPATIAL;
  int x0 = lane*8;
  int sp0 = y*HW + x0;
  const uint32_t* ub = bits + ((size_t)(bc/CH)<<13);
  f32x8 iv = *(const f32x8*)(img+base+sp0);
  f32x8 nv = *(const f32x8*)(noise+base+sp0);
  h16x8 xc = *(const h16x8*)(xv+base+sp0);
  uint32_t wb = ub[y*16 + (lane>>2)];
  int bit0 = (lane&3)*8;
  f32x8 ov;
  #pragma unroll
  for (int e=0;e<8;e++){
    ov[e] = ((wb>>(bit0+e))&1u) ? ((float)xc[e] + 0.01f*nv[e]) : iv[e];
  }
  *(f32x8*)(out+base+sp0) = ov;
}

extern "C" void kernel_launch(void* const* d_in, const int* in_sizes, int n_in,
                              void* d_out, int out_size, void* d_ws, size_t ws_size,
                              hipStream_t stream) {
  const float* img  =(const float*)d_in[0];
  const int*   smap =(const int*)d_in[1];
  const float* noise=(const float*)d_in[2];
  float* out=(float*)d_out;
  float* maskout = out + NELEM;          // mask output region (B,H,W)
  char* ws=(char*)d_ws;
  h16* pbuf[3] = { (h16*)(ws+OFF_P0), (h16*)(ws+OFF_P1), (h16*)(ws+OFF_P2) };
  h16* xv =(h16*)(ws+OFF_X);
  uint32_t* bits=(uint32_t*)(ws+OFF_BITS);
  double* dots=(double*)(ws+OFF_DOTS);
  double* betas=(double*)(ws+OFF_BETA);
  double* alphas=(double*)(ws+OFF_ALPH);
  int* hc=(int*)(ws+OFF_HC);
  int* hf=(int*)(ws+OFF_HF);
  int* sel=(int*)(ws+OFF_SEL);
  int* tiecnt=(int*)(ws+OFF_TC);
  int* tielist=(int*)(ws+OFF_TL);

  // zero x, dots, betas/alphas, hists, sel, tiecnt (bits fully overwritten; tielist guarded)
  hipMemsetAsync(ws+OFF_X, 0, OFF_TL-OFF_X, stream);

  // mask pipeline
  k_hist_coarse<<<dim3(64,16),256,0,stream>>>(smap,hc);
  k_select_coarse<<<1,dim3(64,16),0,stream>>>(hc,sel);
  k_hist_fine<<<dim3(64,16),256,0,stream>>>(smap,sel,hf);
  k_select_fine<<<1,dim3(64,16),0,stream>>>(hf,sel);
  k_mask_init<<<SPATIAL*BATCH/256,256,0,stream>>>(smap,sel,maskout,bits,tiecnt,tielist);
  k_tie_fix<<<16,256,0,stream>>>(sel,tiecnt,tielist,maskout,bits);

  // CG: 1536 blocks x (64,4); each wave = 4-row band
  dim3 gcg(NPLANE*(HW/BAND)/4), bcg(64,4);
  k_rhs<<<gcg,bcg,0,stream>>>(img,bits,pbuf[0],dots);

  for (int i=1;i<=NITER;i++){
    const h16* pm1 = pbuf[(i-1)%3];
    const h16* pm2 = (i>=2)? pbuf[(i-2)%3] : pbuf[0];   // i==1: bprev=aprev=0, pm2 unused but finite
    h16* pn        = pbuf[i%3];
    k_cg<<<gcg,bcg,0,stream>>>(pm1,pm2,pn,xv,bits,dots,betas,alphas,i,(i==NITER)?1:0);
  }

  k_final<<<dim3(HW/4,NPLANE),bcg,0,stream>>>(img,noise,bits,xv,out);
}